// Round 2
// baseline (5620.270 us; speedup 1.0000x reference)
//
#include <hip/hip_runtime.h>
#include <hip/hip_bf16.h>

typedef unsigned short u16;
typedef short bf16x8 __attribute__((ext_vector_type(8)));
typedef float f32x4 __attribute__((ext_vector_type(4)));

// ---------- helpers ----------
__device__ __forceinline__ u16 f2bf(float f) {
    union { float f; unsigned u; } v; v.f = f;
    unsigned x = v.u;
    unsigned r = (x + 0x7FFFu + ((x >> 16) & 1u)) >> 16;   // RNE
    return (u16)r;
}

// ---------- K0: zero flags + hbuf (must run every call: harness does not re-poison) ----------
__global__ void zero_init(int* flags, u16* hbuf) {
    int t = threadIdx.x;
    for (int i = t; i < 64 * 16; i += 256) flags[i] = 0;
    for (int i = t; i < 2 * 2 * 4 * 512; i += 256) hbuf[i] = 0;
}

// ---------- K1: embedding gather -> bf16, K padded 300->320 with zeros ----------
__global__ void gather_emb(const int* __restrict__ tokens, const float* __restrict__ emb,
                           u16* __restrict__ xemb) {
    int row = blockIdx.x;            // b*512 + t
    int tok = tokens[row];
    const float* src = emb + (size_t)tok * 300;
    u16* dst = xemb + (size_t)row * 320;
    int c = threadIdx.x;
    if (c < 320) dst[c] = (c < 300) ? f2bf(src[c]) : (u16)0;
    c += 256;
    if (c < 320) dst[c] = (c < 300) ? f2bf(src[c]) : (u16)0;
}

// ---------- K2: transpose + cvt f32[R][C] -> bf16 out[c][r], zero-pad OOB ----------
__global__ void transpose_cvt(const float* __restrict__ in, u16* __restrict__ out,
                              int R, int C, int outR, int ldO) {
    __shared__ float tile[32][33];
    int c0 = blockIdx.x * 32, r0 = blockIdx.y * 32;
    int tx = threadIdx.x & 31, ty = threadIdx.x >> 5;
#pragma unroll
    for (int yy = 0; yy < 4; ++yy) {
        int r = r0 + ty + yy * 8, cc = c0 + tx;
        tile[ty + yy * 8][tx] = (r < R && cc < C) ? in[(size_t)r * C + cc] : 0.f;
    }
    __syncthreads();
#pragma unroll
    for (int yy = 0; yy < 4; ++yy) {
        int c = c0 + ty + yy * 8, r = r0 + tx;
        if (c < outR && r < ldO) out[(size_t)c * ldO + r] = f2bf(tile[tx][ty + yy * 8]);
    }
}

// ---------- K3: flat f32->bf16 ----------
__global__ void cvt_flat(const float* __restrict__ in, u16* __restrict__ out, int n) {
    for (int i = blockIdx.x * 256 + threadIdx.x; i < n; i += gridDim.x * 256)
        out[i] = f2bf(in[i]);
}

// ---------- K4: generic bf16 MFMA GEMM: C[M,N] = A[M,K] @ BT[N,K]^T (+bias) ----------
// 128x128 tile, BK=32, 256 thr (4 waves, each a 64x64 quadrant of 4x4 16x16 frags).
// LDS tile rows padded 64B->80B (non-pow2 pitch: ~2-way bank conflicts, bijective, no swizzle).
// arev: A-row time-reverse within 512-blocks; orev: same on output rows; orow_base added to out row.
__global__ __launch_bounds__(256) void gemm_bf16(
    const u16* __restrict__ A, const u16* __restrict__ BT,
    float* __restrict__ Cf, u16* __restrict__ Cb,
    const float* __restrict__ bias,
    int M, int Nreal, int K, int ldA, int ldB, int ldC,
    int arev, int orev, int orow_base)
{
    __shared__ char As[128 * 80];
    __shared__ char Bs[128 * 80];
    const int tid = threadIdx.x;
    const int lane = tid & 63;
    const int wid = tid >> 6;
    const int wr = wid >> 1, wc = wid & 1;
    const int m0 = blockIdx.y * 128;
    const int n0 = blockIdx.x * 128;

    f32x4 zero4 = {0.f, 0.f, 0.f, 0.f};
    f32x4 acc[4][4];
#pragma unroll
    for (int i = 0; i < 4; ++i)
#pragma unroll
        for (int j = 0; j < 4; ++j) acc[i][j] = zero4;

    const int kIters = K >> 5;
    const int l15 = lane & 15, kg = lane >> 4;

    for (int kt = 0; kt < kIters; ++kt) {
        int k0 = kt * 32;
        float4 ra[2], rb[2];
#pragma unroll
        for (int i = 0; i < 2; ++i) {
            int id = tid + i * 256;
            int row = id >> 2, ch = id & 3;
            int am = m0 + row;
            if (arev) am = (am & ~511) | (511 - (am & 511));
            ra[i] = *(const float4*)(A + (size_t)am * ldA + k0 + ch * 8);
            rb[i] = *(const float4*)(BT + (size_t)(n0 + row) * ldB + k0 + ch * 8);
        }
        __syncthreads();
#pragma unroll
        for (int i = 0; i < 2; ++i) {
            int id = tid + i * 256;
            int row = id >> 2, ch = id & 3;
            *(float4*)(As + row * 80 + ch * 16) = ra[i];
            *(float4*)(Bs + row * 80 + ch * 16) = rb[i];
        }
        __syncthreads();
        bf16x8 af[4], bfr[4];
#pragma unroll
        for (int mt = 0; mt < 4; ++mt) {
            int r = wr * 64 + mt * 16 + l15;
            af[mt] = *(const bf16x8*)(As + r * 80 + kg * 16);
        }
#pragma unroll
        for (int nt = 0; nt < 4; ++nt) {
            int r = wc * 64 + nt * 16 + l15;
            bfr[nt] = *(const bf16x8*)(Bs + r * 80 + kg * 16);
        }
#pragma unroll
        for (int mt = 0; mt < 4; ++mt)
#pragma unroll
            for (int nt = 0; nt < 4; ++nt)
                acc[mt][nt] = __builtin_amdgcn_mfma_f32_16x16x32_bf16(af[mt], bfr[nt], acc[mt][nt], 0, 0, 0);
    }

#pragma unroll
    for (int nt = 0; nt < 4; ++nt) {
        int col = n0 + wc * 64 + nt * 16 + l15;
        float bv = (bias != nullptr && col < Nreal) ? bias[col] : 0.f;
#pragma unroll
        for (int mt = 0; mt < 4; ++mt) {
#pragma unroll
            for (int j = 0; j < 4; ++j) {
                int m = m0 + wr * 64 + mt * 16 + kg * 4 + j;
                int om = orev ? ((m & ~511) | (511 - (m & 511))) : m;
                om += orow_base;
                if (col < Nreal) {
                    float v = acc[mt][nt][j] + bv;
                    if (Cf) Cf[(size_t)om * ldC + col] = v;
                    else    Cb[(size_t)om * ldC + col] = f2bf(v);
                }
            }
        }
    }
}

// ---------- K5: persistent bidirectional LSTM recurrence ----------
// grid = 64 blocks: dir = bid>>5 (0 fwd, 1 bwd), blk = bid&31 owns 16 hidden units.
// Wc = W_proj @ W_hh pre-folded; h_pre recurrence: p = xp[t] + h_pre_{t-1} @ Wc.
// Wc slice kept in registers as MFMA B-fragments. One flag sync per step.
__global__ __launch_bounds__(256) void lstm_rec(
    const float* __restrict__ Wc_f, const float* __restrict__ Wc_b,
    const float* __restrict__ xp_f, const float* __restrict__ xp_b,
    u16* __restrict__ hbuf, u16* __restrict__ hpre_f, u16* __restrict__ hpre_b,
    int* __restrict__ flags)
{
    __shared__ float gsum[4][4][16];   // [gate][batch][hu]
    __shared__ float cbuf[4][16];
    const int tid = threadIdx.x;
    const int dir = blockIdx.x >> 5;
    const int blk = blockIdx.x & 31;
    const int lane = tid & 63;
    const int wid = tid >> 6;          // wave = gate
    const int l15 = lane & 15;         // A-row (batch) and B-col (hu) index
    const int kg = lane >> 4;

    const float* wcsrc = dir ? Wc_b : Wc_f;
    const float* xp = dir ? xp_b : xp_f;
    u16* hpre = dir ? hpre_b : hpre_f;

    // load Wc B-fragments into registers (one-time scattered read, L2/L3-resident)
    bf16x8 wcf[16];
#pragma unroll
    for (int ks = 0; ks < 16; ++ks) {
        bf16x8 w;
#pragma unroll
        for (int e = 0; e < 8; ++e) {
            int k = ks * 32 + kg * 8 + e;
            w[e] = (short)f2bf(wcsrc[(size_t)k * 2048 + wid * 512 + blk * 16 + l15]);
        }
        wcf[ks] = w;
    }
    if (tid < 64) cbuf[tid >> 4][tid & 15] = 0.f;
    __syncthreads();

    const bf16x8 zero8 = {0, 0, 0, 0, 0, 0, 0, 0};
    int* myflag = &flags[(dir * 32 + blk) * 16];

    for (int t = 0; t < 512; ++t) {
        // prefetch xp (independent of h) — overlaps the spin
        float xpv0 = 0.f, xpv1 = 0.f, xpv2 = 0.f, xpv3 = 0.f;
        int b = tid >> 4, hu = tid & 15;
        if (tid < 64) {
            const float* xr = xp + ((size_t)(b * 512 + t)) * 2048 + blk * 16 + hu;
            xpv0 = xr[0]; xpv1 = xr[512]; xpv2 = xr[1024]; xpv3 = xr[1536];
        }
        if (t > 0) {
            if (tid < 32) {
                while (__hip_atomic_load(&flags[(dir * 32 + tid) * 16],
                                         __ATOMIC_RELAXED, __HIP_MEMORY_SCOPE_AGENT) < t) {}
            }
            __syncthreads();
            __builtin_amdgcn_fence(__ATOMIC_ACQUIRE, "agent");
        }
        // p-slice for this wave's gate: [16(batch-pad) x 16 hu] over K=512
        const u16* hbase = hbuf + (size_t)(dir * 2 + ((t + 1) & 1)) * 4 * 512;
        f32x4 acc = {0.f, 0.f, 0.f, 0.f};
#pragma unroll
        for (int ks = 0; ks < 16; ++ks) {
            bf16x8 a = zero8;
            if (l15 < 4) a = *(const bf16x8*)(hbase + (size_t)l15 * 512 + ks * 32 + kg * 8);
            acc = __builtin_amdgcn_mfma_f32_16x16x32_bf16(a, wcf[ks], acc, 0, 0, 0);
        }
        if (lane < 16) {
#pragma unroll
            for (int j = 0; j < 4; ++j) gsum[wid][j][lane] = acc[j];
        }
        __syncthreads();
        if (tid < 64) {
            float pi = xpv0 + gsum[0][b][hu];
            float pf = xpv1 + gsum[1][b][hu];
            float pg = xpv2 + gsum[2][b][hu];
            float po = xpv3 + gsum[3][b][hu];
            float iv = 1.f / (1.f + expf(-pi));
            float fv = 1.f / (1.f + expf(-pf));
            float gv = tanhf(pg);
            float ov = 1.f / (1.f + expf(-po));
            float c2 = iv * gv + fv * cbuf[b][hu];
            cbuf[b][hu] = c2;
            u16 hpb = f2bf(ov * tanhf(c2));
            hbuf[(size_t)(dir * 2 + (t & 1)) * 4 * 512 + b * 512 + blk * 16 + hu] = hpb;
            hpre[(size_t)(b * 512 + t) * 512 + blk * 16 + hu] = hpb;
        }
        __builtin_amdgcn_fence(__ATOMIC_RELEASE, "agent");
        __syncthreads();
        if (tid == 0)
            __hip_atomic_store(myflag, t + 1, __ATOMIC_RELEASE, __HIP_MEMORY_SCOPE_AGENT);
    }
}

// ---------- host ----------
extern "C" void kernel_launch(void* const* d_in, const int* in_sizes, int n_in,
                              void* d_out, int out_size, void* d_ws, size_t ws_size,
                              hipStream_t stream) {
    const int*   tokens   = (const int*)d_in[0];
    const float* emb      = (const float*)d_in[1];
    const float* W_ih_f   = (const float*)d_in[2];
    const float* W_hh_f   = (const float*)d_in[3];
    const float* b_f      = (const float*)d_in[4];
    const float* W_proj_f = (const float*)d_in[5];
    const float* W_ih_b   = (const float*)d_in[6];
    const float* W_hh_b   = (const float*)d_in[7];
    const float* b_b      = (const float*)d_in[8];
    const float* W_proj_b = (const float*)d_in[9];
    const float* W_lin    = (const float*)d_in[10];
    const float* b_lin    = (const float*)d_in[11];
    float* out = (float*)d_out;

    char* ws = (char*)d_ws;
    size_t off = 0;
    auto alloc = [&](size_t bytes) -> char* {
        char* p = ws + off;
        off = (off + bytes + 255) & ~(size_t)255;
        return p;
    };
    u16* xemb     = (u16*)alloc(2048 * 320 * 2);
    u16* WT_ihf   = (u16*)alloc(2048 * 320 * 2);
    u16* WT_ihb   = (u16*)alloc(2048 * 320 * 2);
    u16* WT_hhf   = (u16*)alloc(2048 * 512 * 2);
    u16* WT_hhb   = (u16*)alloc(2048 * 512 * 2);
    u16* WprojTf  = (u16*)alloc(512 * 512 * 2);
    u16* WprojTb  = (u16*)alloc(512 * 512 * 2);
    u16* WprojAf  = (u16*)alloc(512 * 512 * 2);
    u16* WprojAb  = (u16*)alloc(512 * 512 * 2);
    u16* WT_lin   = (u16*)alloc((size_t)50304 * 512 * 2);
    float* xpf    = (float*)alloc((size_t)2048 * 2048 * 4);
    float* xpb    = (float*)alloc((size_t)2048 * 2048 * 4);
    float* Wc32f  = (float*)alloc((size_t)512 * 2048 * 4);
    float* Wc32b  = (float*)alloc((size_t)512 * 2048 * 4);
    u16* hpref    = (u16*)alloc((size_t)2048 * 512 * 2);
    u16* hpreb    = (u16*)alloc((size_t)2048 * 512 * 2);
    u16* hall     = (u16*)alloc((size_t)4096 * 512 * 2);
    u16* hbuf     = (u16*)alloc(2 * 2 * 4 * 512 * 2);
    int* flags    = (int*)alloc(64 * 16 * 4);

    zero_init<<<1, 256, 0, stream>>>(flags, hbuf);
    gather_emb<<<2048, 256, 0, stream>>>(tokens, emb, xemb);

    transpose_cvt<<<dim3(64, 10), 256, 0, stream>>>(W_ih_f, WT_ihf, 300, 2048, 2048, 320);
    transpose_cvt<<<dim3(64, 10), 256, 0, stream>>>(W_ih_b, WT_ihb, 300, 2048, 2048, 320);
    transpose_cvt<<<dim3(64, 16), 256, 0, stream>>>(W_hh_f, WT_hhf, 512, 2048, 2048, 512);
    transpose_cvt<<<dim3(64, 16), 256, 0, stream>>>(W_hh_b, WT_hhb, 512, 2048, 2048, 512);
    transpose_cvt<<<dim3(16, 16), 256, 0, stream>>>(W_proj_f, WprojTf, 512, 512, 512, 512);
    transpose_cvt<<<dim3(16, 16), 256, 0, stream>>>(W_proj_b, WprojTb, 512, 512, 512, 512);
    transpose_cvt<<<dim3(1572, 16), 256, 0, stream>>>(W_lin, WT_lin, 512, 50257, 50304, 512);
    cvt_flat<<<512, 256, 0, stream>>>(W_proj_f, WprojAf, 512 * 512);
    cvt_flat<<<512, 256, 0, stream>>>(W_proj_b, WprojAb, 512 * 512);

    // xp = (emb gather) @ W_ih + b   (bias of state_linearity folded in; bwd uses time-reversed rows)
    gemm_bf16<<<dim3(16, 16), 256, 0, stream>>>(xemb, WT_ihf, xpf, nullptr, b_f,
                                                2048, 2048, 320, 320, 320, 2048, 0, 0, 0);
    gemm_bf16<<<dim3(16, 16), 256, 0, stream>>>(xemb, WT_ihb, xpb, nullptr, b_b,
                                                2048, 2048, 320, 320, 320, 2048, 1, 0, 0);
    // Wc = W_proj @ W_hh
    gemm_bf16<<<dim3(16, 4), 256, 0, stream>>>(WprojAf, WT_hhf, Wc32f, nullptr, nullptr,
                                               512, 2048, 512, 512, 512, 2048, 0, 0, 0);
    gemm_bf16<<<dim3(16, 4), 256, 0, stream>>>(WprojAb, WT_hhb, Wc32b, nullptr, nullptr,
                                               512, 2048, 512, 512, 512, 2048, 0, 0, 0);

    lstm_rec<<<64, 256, 0, stream>>>(Wc32f, Wc32b, xpf, xpb, hbuf, hpref, hpreb, flags);

    // h = h_pre @ W_proj  (bwd output rows time-reversed, offset 2048)
    gemm_bf16<<<dim3(4, 16), 256, 0, stream>>>(hpref, WprojTf, nullptr, hall, nullptr,
                                               2048, 512, 512, 512, 512, 512, 0, 0, 0);
    gemm_bf16<<<dim3(4, 16), 256, 0, stream>>>(hpreb, WprojTb, nullptr, hall, nullptr,
                                               2048, 512, 512, 512, 512, 512, 0, 1, 2048);
    // logits = h @ W_lin + b_lin
    gemm_bf16<<<dim3(393, 32), 256, 0, stream>>>(hall, WT_lin, out, nullptr, b_lin,
                                                 4096, 50257, 512, 512, 512, 50257, 0, 0, 0);
}

// Round 3
// 2583.624 us; speedup vs baseline: 2.1753x; 2.1753x over previous
//
#include <hip/hip_runtime.h>
#include <hip/hip_bf16.h>

typedef unsigned short u16;
typedef unsigned int u32;
typedef unsigned long long u64;
typedef short bf16x8 __attribute__((ext_vector_type(8)));
typedef float f32x4 __attribute__((ext_vector_type(4)));

// ---------- helpers ----------
__device__ __forceinline__ u16 f2bf(float f) {
    union { float f; unsigned u; } v; v.f = f;
    unsigned x = v.u;
    unsigned r = (x + 0x7FFFu + ((x >> 16) & 1u)) >> 16;   // RNE
    return (u16)r;
}

// ---------- K0: zero tagged h-exchange buffer (harness does not re-poison between replays) ----------
__global__ void zero_init(u64* htag) {
    for (int i = threadIdx.x; i < 2 * 2 * 4 * 256; i += 256) htag[i] = 0ull;
}

// ---------- K1: embedding gather -> bf16, K padded 300->320 with zeros ----------
__global__ void gather_emb(const int* __restrict__ tokens, const float* __restrict__ emb,
                           u16* __restrict__ xemb) {
    int row = blockIdx.x;            // b*512 + t
    int tok = tokens[row];
    const float* src = emb + (size_t)tok * 300;
    u16* dst = xemb + (size_t)row * 320;
    int c = threadIdx.x;
    if (c < 320) dst[c] = (c < 300) ? f2bf(src[c]) : (u16)0;
    c += 256;
    if (c < 320) dst[c] = (c < 300) ? f2bf(src[c]) : (u16)0;
}

// ---------- K2: transpose + cvt f32[R][C] -> bf16 out[c][r], zero-pad OOB ----------
__global__ void transpose_cvt(const float* __restrict__ in, u16* __restrict__ out,
                              int R, int C, int outR, int ldO) {
    __shared__ float tile[32][33];
    int c0 = blockIdx.x * 32, r0 = blockIdx.y * 32;
    int tx = threadIdx.x & 31, ty = threadIdx.x >> 5;
#pragma unroll
    for (int yy = 0; yy < 4; ++yy) {
        int r = r0 + ty + yy * 8, cc = c0 + tx;
        tile[ty + yy * 8][tx] = (r < R && cc < C) ? in[(size_t)r * C + cc] : 0.f;
    }
    __syncthreads();
#pragma unroll
    for (int yy = 0; yy < 4; ++yy) {
        int c = c0 + ty + yy * 8, r = r0 + tx;
        if (c < outR && r < ldO) out[(size_t)c * ldO + r] = f2bf(tile[tx][ty + yy * 8]);
    }
}

// ---------- K3: flat f32->bf16 ----------
__global__ void cvt_flat(const float* __restrict__ in, u16* __restrict__ out, int n) {
    for (int i = blockIdx.x * 256 + threadIdx.x; i < n; i += gridDim.x * 256)
        out[i] = f2bf(in[i]);
}

// ---------- K4: generic bf16 MFMA GEMM: C[M,N] = A[M,K] @ BT[N,K]^T (+bias) ----------
// 128x128 tile, BK=32, 256 thr (4 waves, each a 64x64 quadrant of 4x4 16x16 frags).
// LDS tile rows padded 64B->80B (non-pow2 pitch: ~2-way bank conflicts, bijective, no swizzle).
// arev: A-row time-reverse within 512-blocks; orev: same on output rows; orow_base added to out row.
__global__ __launch_bounds__(256) void gemm_bf16(
    const u16* __restrict__ A, const u16* __restrict__ BT,
    float* __restrict__ Cf, u16* __restrict__ Cb,
    const float* __restrict__ bias,
    int M, int Nreal, int K, int ldA, int ldB, int ldC,
    int arev, int orev, int orow_base)
{
    __shared__ char As[128 * 80];
    __shared__ char Bs[128 * 80];
    const int tid = threadIdx.x;
    const int lane = tid & 63;
    const int wid = tid >> 6;
    const int wr = wid >> 1, wc = wid & 1;
    const int m0 = blockIdx.y * 128;
    const int n0 = blockIdx.x * 128;

    f32x4 zero4 = {0.f, 0.f, 0.f, 0.f};
    f32x4 acc[4][4];
#pragma unroll
    for (int i = 0; i < 4; ++i)
#pragma unroll
        for (int j = 0; j < 4; ++j) acc[i][j] = zero4;

    const int kIters = K >> 5;
    const int l15 = lane & 15, kg = lane >> 4;

    for (int kt = 0; kt < kIters; ++kt) {
        int k0 = kt * 32;
        float4 ra[2], rb[2];
#pragma unroll
        for (int i = 0; i < 2; ++i) {
            int id = tid + i * 256;
            int row = id >> 2, ch = id & 3;
            int am = m0 + row;
            if (arev) am = (am & ~511) | (511 - (am & 511));
            ra[i] = *(const float4*)(A + (size_t)am * ldA + k0 + ch * 8);
            rb[i] = *(const float4*)(BT + (size_t)(n0 + row) * ldB + k0 + ch * 8);
        }
        __syncthreads();
#pragma unroll
        for (int i = 0; i < 2; ++i) {
            int id = tid + i * 256;
            int row = id >> 2, ch = id & 3;
            *(float4*)(As + row * 80 + ch * 16) = ra[i];
            *(float4*)(Bs + row * 80 + ch * 16) = rb[i];
        }
        __syncthreads();
        bf16x8 af[4], bfr[4];
#pragma unroll
        for (int mt = 0; mt < 4; ++mt) {
            int r = wr * 64 + mt * 16 + l15;
            af[mt] = *(const bf16x8*)(As + r * 80 + kg * 16);
        }
#pragma unroll
        for (int nt = 0; nt < 4; ++nt) {
            int r = wc * 64 + nt * 16 + l15;
            bfr[nt] = *(const bf16x8*)(Bs + r * 80 + kg * 16);
        }
#pragma unroll
        for (int mt = 0; mt < 4; ++mt)
#pragma unroll
            for (int nt = 0; nt < 4; ++nt)
                acc[mt][nt] = __builtin_amdgcn_mfma_f32_16x16x32_bf16(af[mt], bfr[nt], acc[mt][nt], 0, 0, 0);
    }

#pragma unroll
    for (int nt = 0; nt < 4; ++nt) {
        int col = n0 + wc * 64 + nt * 16 + l15;
        float bv = (bias != nullptr && col < Nreal) ? bias[col] : 0.f;
#pragma unroll
        for (int mt = 0; mt < 4; ++mt) {
#pragma unroll
            for (int j = 0; j < 4; ++j) {
                int m = m0 + wr * 64 + mt * 16 + kg * 4 + j;
                int om = orev ? ((m & ~511) | (511 - (m & 511))) : m;
                om += orow_base;
                if (col < Nreal) {
                    float v = acc[mt][nt][j] + bv;
                    if (Cf) Cf[(size_t)om * ldC + col] = v;
                    else    Cb[(size_t)om * ldC + col] = f2bf(v);
                }
            }
        }
    }
}

// ---------- K5: persistent bidirectional LSTM recurrence, fence-free ----------
// grid = 64 blocks: dir = bid>>5, blk = bid&31 owns 16 hidden units of that direction.
// Cross-block exchange via relaxed agent-scope (coherence-point) atomics ONLY — no fences.
// Each published u64 = (tag=t+1)<<32 | two bf16 h-values. Readers spin on the tagged words
// themselves (data+flag in one load). Parity double-buffer on t&1; safety: a block can only
// publish tag u+1 after observing ALL tags u, which proves every block finished reading u-1.
__global__ __launch_bounds__(256) void lstm_rec(
    const float* __restrict__ Wc_f, const float* __restrict__ Wc_b,
    const float* __restrict__ xp_f, const float* __restrict__ xp_b,
    u64* __restrict__ htag,
    u16* __restrict__ hpre_f, u16* __restrict__ hpre_b)
{
    __shared__ u16 hlds[4][520];       // staged h (4 batch x 512 hu), row padded +8 u16
    __shared__ float gsum[4][4][16];   // [gate][batch][hu]
    __shared__ float cbuf[4][16];
    const int tid = threadIdx.x;
    const int dir = blockIdx.x >> 5;
    const int blk = blockIdx.x & 31;
    const int lane = tid & 63;
    const int wid = tid >> 6;          // wave = gate
    const int l15 = lane & 15;
    const int kg = lane >> 4;          // 0..3: K-subgroup within fragment

    const float* wcsrc = dir ? Wc_b : Wc_f;
    const float* xp    = dir ? xp_b : xp_f;
    u16* hpre          = dir ? hpre_b : hpre_f;
    u64* ht            = htag + (size_t)dir * 2 * 4 * 256;   // [slot][b][256 words]

    // load Wc B-fragments into registers (one-time scattered read, L2/L3-resident)
    bf16x8 wcf[16];
#pragma unroll
    for (int ks = 0; ks < 16; ++ks) {
        bf16x8 w;
#pragma unroll
        for (int e = 0; e < 8; ++e) {
            int k = ks * 32 + kg * 8 + e;
            w[e] = (short)f2bf(wcsrc[(size_t)k * 2048 + wid * 512 + blk * 16 + l15]);
        }
        wcf[ks] = w;
    }
    if (tid < 64) cbuf[tid >> 4][tid & 15] = 0.f;
    __syncthreads();

    const bf16x8 zero8 = {0, 0, 0, 0, 0, 0, 0, 0};

    for (int t = 0; t < 512; ++t) {
        // xp prefetch (independent of h) — issues before the spin
        float xpv0 = 0.f, xpv1 = 0.f, xpv2 = 0.f, xpv3 = 0.f;
        const int b = tid >> 4, hu = tid & 15;
        if (tid < 64) {
            const float* xr = xp + ((size_t)(b * 512 + t)) * 2048 + blk * 16 + hu;
            xpv0 = xr[0]; xpv1 = xr[512]; xpv2 = xr[1024]; xpv3 = xr[1536];
        }
        // cooperative tagged staging: thread tid owns word-column tid of all 4 batch rows
        {
            const u64* src = ht + (size_t)(t & 1) * 4 * 256;
            const u32 target = (u32)t;
            u64 w0, w1, w2, w3;
            for (;;) {
                w0 = __hip_atomic_load(&src[0 * 256 + tid], __ATOMIC_RELAXED, __HIP_MEMORY_SCOPE_AGENT);
                w1 = __hip_atomic_load(&src[1 * 256 + tid], __ATOMIC_RELAXED, __HIP_MEMORY_SCOPE_AGENT);
                w2 = __hip_atomic_load(&src[2 * 256 + tid], __ATOMIC_RELAXED, __HIP_MEMORY_SCOPE_AGENT);
                w3 = __hip_atomic_load(&src[3 * 256 + tid], __ATOMIC_RELAXED, __HIP_MEMORY_SCOPE_AGENT);
                if (((u32)(w0 >> 32) == target) & ((u32)(w1 >> 32) == target) &
                    ((u32)(w2 >> 32) == target) & ((u32)(w3 >> 32) == target)) break;
                __builtin_amdgcn_s_sleep(1);   // throttle fabric poll traffic
            }
            asm volatile("" ::: "memory");
            *(u32*)&hlds[0][tid * 2] = (u32)w0;
            *(u32*)&hlds[1][tid * 2] = (u32)w1;
            *(u32*)&hlds[2][tid * 2] = (u32)w2;
            *(u32*)&hlds[3][tid * 2] = (u32)w3;
        }
        __syncthreads();   // SYNC_A: staging -> fragment reads (also protects gsum reuse)

        // p-slice for this wave's gate: [16(batch-pad) x 16 hu] over K=512; 2 chains for ILP
        f32x4 acc0 = {0.f, 0.f, 0.f, 0.f}, acc1 = {0.f, 0.f, 0.f, 0.f};
#pragma unroll
        for (int ks = 0; ks < 16; ++ks) {
            bf16x8 a = zero8;
            if (l15 < 4) a = *(const bf16x8*)&hlds[l15][ks * 32 + kg * 8];
            if (ks & 1) acc1 = __builtin_amdgcn_mfma_f32_16x16x32_bf16(a, wcf[ks], acc1, 0, 0, 0);
            else        acc0 = __builtin_amdgcn_mfma_f32_16x16x32_bf16(a, wcf[ks], acc0, 0, 0, 0);
        }
        f32x4 accs = acc0 + acc1;
        if (lane < 16) {
#pragma unroll
            for (int j = 0; j < 4; ++j) gsum[wid][j][lane] = accs[j];
        }
        __syncthreads();   // SYNC_B: gsum -> gate math (also protects hlds reuse)

        if (tid < 64) {
            float pi = xpv0 + gsum[0][b][hu];
            float pf = xpv1 + gsum[1][b][hu];
            float pg = xpv2 + gsum[2][b][hu];
            float po = xpv3 + gsum[3][b][hu];
            float iv = 1.f / (1.f + expf(-pi));
            float fv = 1.f / (1.f + expf(-pf));
            float gv = tanhf(pg);
            float ov = 1.f / (1.f + expf(-po));
            float c2 = iv * gv + fv * cbuf[b][hu];
            cbuf[b][hu] = c2;
            u16 hpb = f2bf(ov * tanhf(c2));
            hpre[(size_t)(b * 512 + t) * 512 + blk * 16 + hu] = hpb;
            // publish: pack pairs via shuffle, tag with t+1, store to parity slot (t+1)&1
            unsigned v = hpb;
            unsigned nb = (unsigned)__shfl_down((int)v, 1);
            if ((tid & 1) == 0) {
                u32 packed = v | (nb << 16);
                u64 val = ((u64)(u32)(t + 1) << 32) | (u64)packed;
                size_t idx = (size_t)(((t + 1) & 1) * 4 + b) * 256 + blk * 8 + (hu >> 1);
                __hip_atomic_store(&ht[idx], val, __ATOMIC_RELAXED, __HIP_MEMORY_SCOPE_AGENT);
            }
        }
    }
}

// ---------- host ----------
extern "C" void kernel_launch(void* const* d_in, const int* in_sizes, int n_in,
                              void* d_out, int out_size, void* d_ws, size_t ws_size,
                              hipStream_t stream) {
    const int*   tokens   = (const int*)d_in[0];
    const float* emb      = (const float*)d_in[1];
    const float* W_ih_f   = (const float*)d_in[2];
    const float* W_hh_f   = (const float*)d_in[3];
    const float* b_f      = (const float*)d_in[4];
    const float* W_proj_f = (const float*)d_in[5];
    const float* W_ih_b   = (const float*)d_in[6];
    const float* W_hh_b   = (const float*)d_in[7];
    const float* b_b      = (const float*)d_in[8];
    const float* W_proj_b = (const float*)d_in[9];
    const float* W_lin    = (const float*)d_in[10];
    const float* b_lin    = (const float*)d_in[11];
    float* out = (float*)d_out;

    char* ws = (char*)d_ws;
    size_t off = 0;
    auto alloc = [&](size_t bytes) -> char* {
        char* p = ws + off;
        off = (off + bytes + 255) & ~(size_t)255;
        return p;
    };
    u16* xemb     = (u16*)alloc(2048 * 320 * 2);
    u16* WT_ihf   = (u16*)alloc(2048 * 320 * 2);
    u16* WT_ihb   = (u16*)alloc(2048 * 320 * 2);
    u16* WT_hhf   = (u16*)alloc(2048 * 512 * 2);
    u16* WT_hhb   = (u16*)alloc(2048 * 512 * 2);
    u16* WprojTf  = (u16*)alloc(512 * 512 * 2);
    u16* WprojTb  = (u16*)alloc(512 * 512 * 2);
    u16* WprojAf  = (u16*)alloc(512 * 512 * 2);
    u16* WprojAb  = (u16*)alloc(512 * 512 * 2);
    u16* WT_lin   = (u16*)alloc((size_t)50304 * 512 * 2);
    float* xpf    = (float*)alloc((size_t)2048 * 2048 * 4);
    float* xpb    = (float*)alloc((size_t)2048 * 2048 * 4);
    float* Wc32f  = (float*)alloc((size_t)512 * 2048 * 4);
    float* Wc32b  = (float*)alloc((size_t)512 * 2048 * 4);
    u16* hpref    = (u16*)alloc((size_t)2048 * 512 * 2);
    u16* hpreb    = (u16*)alloc((size_t)2048 * 512 * 2);
    u16* hall     = (u16*)alloc((size_t)4096 * 512 * 2);
    u64* htag     = (u64*)alloc((size_t)2 * 2 * 4 * 256 * 8);

    zero_init<<<1, 256, 0, stream>>>(htag);
    gather_emb<<<2048, 256, 0, stream>>>(tokens, emb, xemb);

    transpose_cvt<<<dim3(64, 10), 256, 0, stream>>>(W_ih_f, WT_ihf, 300, 2048, 2048, 320);
    transpose_cvt<<<dim3(64, 10), 256, 0, stream>>>(W_ih_b, WT_ihb, 300, 2048, 2048, 320);
    transpose_cvt<<<dim3(64, 16), 256, 0, stream>>>(W_hh_f, WT_hhf, 512, 2048, 2048, 512);
    transpose_cvt<<<dim3(64, 16), 256, 0, stream>>>(W_hh_b, WT_hhb, 512, 2048, 2048, 512);
    transpose_cvt<<<dim3(16, 16), 256, 0, stream>>>(W_proj_f, WprojTf, 512, 512, 512, 512);
    transpose_cvt<<<dim3(16, 16), 256, 0, stream>>>(W_proj_b, WprojTb, 512, 512, 512, 512);
    transpose_cvt<<<dim3(1572, 16), 256, 0, stream>>>(W_lin, WT_lin, 512, 50257, 50304, 512);
    cvt_flat<<<512, 256, 0, stream>>>(W_proj_f, WprojAf, 512 * 512);
    cvt_flat<<<512, 256, 0, stream>>>(W_proj_b, WprojAb, 512 * 512);

    // xp = (emb gather) @ W_ih + b   (state_linearity bias folded in; bwd uses time-reversed rows)
    gemm_bf16<<<dim3(16, 16), 256, 0, stream>>>(xemb, WT_ihf, xpf, nullptr, b_f,
                                                2048, 2048, 320, 320, 320, 2048, 0, 0, 0);
    gemm_bf16<<<dim3(16, 16), 256, 0, stream>>>(xemb, WT_ihb, xpb, nullptr, b_b,
                                                2048, 2048, 320, 320, 320, 2048, 1, 0, 0);
    // Wc = W_proj @ W_hh
    gemm_bf16<<<dim3(16, 4), 256, 0, stream>>>(WprojAf, WT_hhf, Wc32f, nullptr, nullptr,
                                               512, 2048, 512, 512, 512, 2048, 0, 0, 0);
    gemm_bf16<<<dim3(16, 4), 256, 0, stream>>>(WprojAb, WT_hhb, Wc32b, nullptr, nullptr,
                                               512, 2048, 512, 512, 512, 2048, 0, 0, 0);

    lstm_rec<<<64, 256, 0, stream>>>(Wc32f, Wc32b, xpf, xpb, htag, hpref, hpreb);

    // h = h_pre @ W_proj  (bwd output rows time-reversed, offset 2048)
    gemm_bf16<<<dim3(4, 16), 256, 0, stream>>>(hpref, WprojTf, nullptr, hall, nullptr,
                                               2048, 512, 512, 512, 512, 512, 0, 0, 0);
    gemm_bf16<<<dim3(4, 16), 256, 0, stream>>>(hpreb, WprojTb, nullptr, hall, nullptr,
                                               2048, 512, 512, 512, 512, 512, 0, 1, 2048);
    // logits = h @ W_lin + b_lin
    gemm_bf16<<<dim3(393, 32), 256, 0, stream>>>(hall, WT_lin, out, nullptr, b_lin,
                                                 4096, 50257, 512, 512, 512, 50257, 0, 0, 0);
}

// Round 4
// 1859.294 us; speedup vs baseline: 3.0228x; 1.3896x over previous
//
#include <hip/hip_runtime.h>
#include <hip/hip_bf16.h>

typedef unsigned short u16;
typedef unsigned int u32;
typedef unsigned long long u64;
typedef short bf16x8 __attribute__((ext_vector_type(8)));
typedef float f32x4 __attribute__((ext_vector_type(4)));

// address-space casts for global_load_lds
#define AS1C(p) ((const __attribute__((address_space(1))) void*)(p))
#define AS3(p)  ((__attribute__((address_space(3))) void*)(p))

// ---------- helpers ----------
__device__ __forceinline__ u16 f2bf(float f) {
    union { float f; unsigned u; } v; v.f = f;
    unsigned x = v.u;
    unsigned r = (x + 0x7FFFu + ((x >> 16) & 1u)) >> 16;   // RNE
    return (u16)r;
}

// ---------- K0: zero tagged h-exchange buffer (harness does not re-poison between replays) ----------
__global__ void zero_init(u64* htag) {
    for (int i = threadIdx.x; i < 2 * 2 * 4 * 256; i += 256) htag[i] = 0ull;
}

// ---------- K1: embedding gather -> bf16, K padded 300->320 with zeros ----------
__global__ void gather_emb(const int* __restrict__ tokens, const float* __restrict__ emb,
                           u16* __restrict__ xemb) {
    int row = blockIdx.x;            // b*512 + t
    int tok = tokens[row];
    const float* src = emb + (size_t)tok * 300;
    u16* dst = xemb + (size_t)row * 320;
    int c = threadIdx.x;
    if (c < 320) dst[c] = (c < 300) ? f2bf(src[c]) : (u16)0;
    c += 256;
    if (c < 320) dst[c] = (c < 300) ? f2bf(src[c]) : (u16)0;
}

// ---------- K2: transpose + cvt f32[R][C] -> bf16 out[c][r], zero-pad OOB ----------
__global__ void transpose_cvt(const float* __restrict__ in, u16* __restrict__ out,
                              int R, int C, int outR, int ldO) {
    __shared__ float tile[32][33];
    int c0 = blockIdx.x * 32, r0 = blockIdx.y * 32;
    int tx = threadIdx.x & 31, ty = threadIdx.x >> 5;
#pragma unroll
    for (int yy = 0; yy < 4; ++yy) {
        int r = r0 + ty + yy * 8, cc = c0 + tx;
        tile[ty + yy * 8][tx] = (r < R && cc < C) ? in[(size_t)r * C + cc] : 0.f;
    }
    __syncthreads();
#pragma unroll
    for (int yy = 0; yy < 4; ++yy) {
        int c = c0 + ty + yy * 8, r = r0 + tx;
        if (c < outR && r < ldO) out[(size_t)c * ldO + r] = f2bf(tile[tx][ty + yy * 8]);
    }
}

// ---------- K3: flat f32->bf16 ----------
__global__ void cvt_flat(const float* __restrict__ in, u16* __restrict__ out, int n) {
    for (int i = blockIdx.x * 256 + threadIdx.x; i < n; i += gridDim.x * 256)
        out[i] = f2bf(in[i]);
}

// ---------- K4: bf16 MFMA GEMM: C[M,N] = A[M,K] @ BT[N,K]^T (+bias) ----------
// 128x128 tile, BK=32, 256 thr (4 waves, 2x2 quadrants of 4x4 16x16x32 frags).
// m97 structure: global_load_lds dwordx4 staging (linear LDS dest, wave base + lane*16),
// source-side XOR pre-swizzle chunk^=(row&3) matched by swizzled ds_read_b128 (rule 21).
// arev: A-row time-reverse within 512-blocks; orev: same on output rows; orow_base added.
__global__ __launch_bounds__(256) void gemm_bf16(
    const u16* __restrict__ A, const u16* __restrict__ BT,
    float* __restrict__ Cf, u16* __restrict__ Cb,
    const float* __restrict__ bias,
    int M, int Nreal, int K, int ldA, int ldB, int ldC,
    int arev, int orev, int orow_base)
{
    __shared__ char As[8192];
    __shared__ char Bs[8192];
    const int tid = threadIdx.x;
    const int lane = tid & 63;
    const int wid = tid >> 6;
    const int wr = wid >> 1, wc = wid & 1;
    const int m0 = blockIdx.y * 128;
    const int n0 = blockIdx.x * 128;

    f32x4 zero4 = {0.f, 0.f, 0.f, 0.f};
    f32x4 acc[4][4];
#pragma unroll
    for (int i = 0; i < 4; ++i)
#pragma unroll
        for (int j = 0; j < 4; ++j) acc[i][j] = zero4;

    const int kIters = K >> 5;
    const int l15 = lane & 15, kg = lane >> 4;

    // staging geometry: issue i of wave wid covers LDS rows wid*32+i*16 .. +15;
    // lane l -> row = base + (l>>2), phys chunk d = l&3 (dest = wavebase + l*16, linear).
    // pre-swizzle: phys chunk d sources logical chunk c = d ^ (row&3).
    const int srow0 = wid * 32 + (lane >> 2);
    const int srow1 = srow0 + 16;
    const int c0 = (lane & 3) ^ (srow0 & 3);
    const int c1 = (lane & 3) ^ (srow1 & 3);
    int ar0 = m0 + srow0, ar1 = m0 + srow1;
    if (arev) {
        ar0 = (ar0 & ~511) | (511 - (ar0 & 511));
        ar1 = (ar1 & ~511) | (511 - (ar1 & 511));
    }
    const u16* ga0 = A + (size_t)ar0 * ldA + c0 * 8;
    const u16* ga1 = A + (size_t)ar1 * ldA + c1 * 8;
    const u16* gb0 = BT + (size_t)(n0 + srow0) * ldB + c0 * 8;
    const u16* gb1 = BT + (size_t)(n0 + srow1) * ldB + c1 * 8;
    char* ldsA0 = As + wid * 2048;
    char* ldsA1 = As + wid * 2048 + 1024;
    char* ldsB0 = Bs + wid * 2048;
    char* ldsB1 = Bs + wid * 2048 + 1024;

    for (int kt = 0; kt < kIters; ++kt) {
        const int k0 = kt * 32;
        __builtin_amdgcn_global_load_lds(AS1C(ga0 + k0), AS3(ldsA0), 16, 0, 0);
        __builtin_amdgcn_global_load_lds(AS1C(ga1 + k0), AS3(ldsA1), 16, 0, 0);
        __builtin_amdgcn_global_load_lds(AS1C(gb0 + k0), AS3(ldsB0), 16, 0, 0);
        __builtin_amdgcn_global_load_lds(AS1C(gb1 + k0), AS3(ldsB1), 16, 0, 0);
        __syncthreads();   // drains vmcnt(0): staged tile visible

        bf16x8 af[4], bfr[4];
#pragma unroll
        for (int mt = 0; mt < 4; ++mt) {
            int r = wr * 64 + mt * 16 + l15;
            af[mt] = *(const bf16x8*)(As + r * 64 + ((kg ^ (r & 3)) * 16));
        }
#pragma unroll
        for (int nt = 0; nt < 4; ++nt) {
            int r = wc * 64 + nt * 16 + l15;
            bfr[nt] = *(const bf16x8*)(Bs + r * 64 + ((kg ^ (r & 3)) * 16));
        }
#pragma unroll
        for (int mt = 0; mt < 4; ++mt)
#pragma unroll
            for (int nt = 0; nt < 4; ++nt)
                acc[mt][nt] = __builtin_amdgcn_mfma_f32_16x16x32_bf16(af[mt], bfr[nt], acc[mt][nt], 0, 0, 0);
        __syncthreads();   // frag reads done before next tile overwrites LDS
    }

#pragma unroll
    for (int nt = 0; nt < 4; ++nt) {
        int col = n0 + wc * 64 + nt * 16 + l15;
        float bv = (bias != nullptr && col < Nreal) ? bias[col] : 0.f;
#pragma unroll
        for (int mt = 0; mt < 4; ++mt) {
#pragma unroll
            for (int j = 0; j < 4; ++j) {
                int m = m0 + wr * 64 + mt * 16 + kg * 4 + j;
                int om = orev ? ((m & ~511) | (511 - (m & 511))) : m;
                om += orow_base;
                if (col < Nreal) {
                    float v = acc[mt][nt][j] + bv;
                    if (Cf) Cf[(size_t)om * ldC + col] = v;
                    else    Cb[(size_t)om * ldC + col] = f2bf(v);
                }
            }
        }
    }
}

// ---------- K5: persistent bidirectional LSTM recurrence, fence-free ----------
// grid = 64 blocks: dir = bid>>5, blk = bid&31 owns 16 hidden units of that direction.
// Cross-block exchange via relaxed agent-scope (coherence-point) atomics ONLY — no fences.
// Each published u64 = (tag=t+1)<<32 | two bf16 h-values. Readers spin on the tagged words
// themselves (data+flag in one load). Parity double-buffer on t&1; safety: a block can only
// publish tag u+1 after observing ALL tags u, which proves every block finished reading u-1.
__global__ __launch_bounds__(256) void lstm_rec(
    const float* __restrict__ Wc_f, const float* __restrict__ Wc_b,
    const float* __restrict__ xp_f, const float* __restrict__ xp_b,
    u64* __restrict__ htag,
    u16* __restrict__ hpre_f, u16* __restrict__ hpre_b)
{
    __shared__ u16 hlds[4][520];       // staged h (4 batch x 512 hu), row padded +8 u16
    __shared__ float gsum[4][4][16];   // [gate][batch][hu]
    __shared__ float cbuf[4][16];
    const int tid = threadIdx.x;
    const int dir = blockIdx.x >> 5;
    const int blk = blockIdx.x & 31;
    const int lane = tid & 63;
    const int wid = tid >> 6;          // wave = gate
    const int l15 = lane & 15;
    const int kg = lane >> 4;          // 0..3: K-subgroup within fragment

    const float* wcsrc = dir ? Wc_b : Wc_f;
    const float* xp    = dir ? xp_b : xp_f;
    u16* hpre          = dir ? hpre_b : hpre_f;
    u64* ht            = htag + (size_t)dir * 2 * 4 * 256;   // [slot][b][256 words]

    // load Wc B-fragments into registers (one-time scattered read, L2/L3-resident)
    bf16x8 wcf[16];
#pragma unroll
    for (int ks = 0; ks < 16; ++ks) {
        bf16x8 w;
#pragma unroll
        for (int e = 0; e < 8; ++e) {
            int k = ks * 32 + kg * 8 + e;
            w[e] = (short)f2bf(wcsrc[(size_t)k * 2048 + wid * 512 + blk * 16 + l15]);
        }
        wcf[ks] = w;
    }
    if (tid < 64) cbuf[tid >> 4][tid & 15] = 0.f;
    __syncthreads();

    const bf16x8 zero8 = {0, 0, 0, 0, 0, 0, 0, 0};

    for (int t = 0; t < 512; ++t) {
        // xp prefetch (independent of h) — issues before the spin
        float xpv0 = 0.f, xpv1 = 0.f, xpv2 = 0.f, xpv3 = 0.f;
        const int b = tid >> 4, hu = tid & 15;
        if (tid < 64) {
            const float* xr = xp + ((size_t)(b * 512 + t)) * 2048 + blk * 16 + hu;
            xpv0 = xr[0]; xpv1 = xr[512]; xpv2 = xr[1024]; xpv3 = xr[1536];
        }
        // cooperative tagged staging: thread tid owns word-column tid of all 4 batch rows
        {
            const u64* src = ht + (size_t)(t & 1) * 4 * 256;
            const u32 target = (u32)t;
            u64 w0, w1, w2, w3;
            for (;;) {
                w0 = __hip_atomic_load(&src[0 * 256 + tid], __ATOMIC_RELAXED, __HIP_MEMORY_SCOPE_AGENT);
                w1 = __hip_atomic_load(&src[1 * 256 + tid], __ATOMIC_RELAXED, __HIP_MEMORY_SCOPE_AGENT);
                w2 = __hip_atomic_load(&src[2 * 256 + tid], __ATOMIC_RELAXED, __HIP_MEMORY_SCOPE_AGENT);
                w3 = __hip_atomic_load(&src[3 * 256 + tid], __ATOMIC_RELAXED, __HIP_MEMORY_SCOPE_AGENT);
                if (((u32)(w0 >> 32) == target) & ((u32)(w1 >> 32) == target) &
                    ((u32)(w2 >> 32) == target) & ((u32)(w3 >> 32) == target)) break;
                __builtin_amdgcn_s_sleep(1);   // throttle fabric poll traffic
            }
            asm volatile("" ::: "memory");
            *(u32*)&hlds[0][tid * 2] = (u32)w0;
            *(u32*)&hlds[1][tid * 2] = (u32)w1;
            *(u32*)&hlds[2][tid * 2] = (u32)w2;
            *(u32*)&hlds[3][tid * 2] = (u32)w3;
        }
        __syncthreads();   // SYNC_A: staging -> fragment reads (also protects gsum reuse)

        // p-slice for this wave's gate: [16(batch-pad) x 16 hu] over K=512; 2 chains for ILP
        f32x4 acc0 = {0.f, 0.f, 0.f, 0.f}, acc1 = {0.f, 0.f, 0.f, 0.f};
#pragma unroll
        for (int ks = 0; ks < 16; ++ks) {
            bf16x8 a = zero8;
            if (l15 < 4) a = *(const bf16x8*)&hlds[l15][ks * 32 + kg * 8];
            if (ks & 1) acc1 = __builtin_amdgcn_mfma_f32_16x16x32_bf16(a, wcf[ks], acc1, 0, 0, 0);
            else        acc0 = __builtin_amdgcn_mfma_f32_16x16x32_bf16(a, wcf[ks], acc0, 0, 0, 0);
        }
        f32x4 accs = acc0 + acc1;
        if (lane < 16) {
#pragma unroll
            for (int j = 0; j < 4; ++j) gsum[wid][j][lane] = accs[j];
        }
        __syncthreads();   // SYNC_B: gsum -> gate math (also protects hlds reuse)

        if (tid < 64) {
            float pi = xpv0 + gsum[0][b][hu];
            float pf = xpv1 + gsum[1][b][hu];
            float pg = xpv2 + gsum[2][b][hu];
            float po = xpv3 + gsum[3][b][hu];
            float iv = 1.f / (1.f + expf(-pi));
            float fv = 1.f / (1.f + expf(-pf));
            float gv = tanhf(pg);
            float ov = 1.f / (1.f + expf(-po));
            float c2 = iv * gv + fv * cbuf[b][hu];
            cbuf[b][hu] = c2;
            u16 hpb = f2bf(ov * tanhf(c2));
            hpre[(size_t)(b * 512 + t) * 512 + blk * 16 + hu] = hpb;
            // publish: pack pairs via shuffle, tag with t+1, store to parity slot (t+1)&1
            unsigned v = hpb;
            unsigned nb = (unsigned)__shfl_down((int)v, 1);
            if ((tid & 1) == 0) {
                u32 packed = v | (nb << 16);
                u64 val = ((u64)(u32)(t + 1) << 32) | (u64)packed;
                size_t idx = (size_t)(((t + 1) & 1) * 4 + b) * 256 + blk * 8 + (hu >> 1);
                __hip_atomic_store(&ht[idx], val, __ATOMIC_RELAXED, __HIP_MEMORY_SCOPE_AGENT);
            }
        }
    }
}

// ---------- host ----------
extern "C" void kernel_launch(void* const* d_in, const int* in_sizes, int n_in,
                              void* d_out, int out_size, void* d_ws, size_t ws_size,
                              hipStream_t stream) {
    const int*   tokens   = (const int*)d_in[0];
    const float* emb      = (const float*)d_in[1];
    const float* W_ih_f   = (const float*)d_in[2];
    const float* W_hh_f   = (const float*)d_in[3];
    const float* b_f      = (const float*)d_in[4];
    const float* W_proj_f = (const float*)d_in[5];
    const float* W_ih_b   = (const float*)d_in[6];
    const float* W_hh_b   = (const float*)d_in[7];
    const float* b_b      = (const float*)d_in[8];
    const float* W_proj_b = (const float*)d_in[9];
    const float* W_lin    = (const float*)d_in[10];
    const float* b_lin    = (const float*)d_in[11];
    float* out = (float*)d_out;

    char* ws = (char*)d_ws;
    size_t off = 0;
    auto alloc = [&](size_t bytes) -> char* {
        char* p = ws + off;
        off = (off + bytes + 255) & ~(size_t)255;
        return p;
    };
    u16* xemb     = (u16*)alloc(2048 * 320 * 2);
    u16* WT_ihf   = (u16*)alloc(2048 * 320 * 2);
    u16* WT_ihb   = (u16*)alloc(2048 * 320 * 2);
    u16* WT_hhf   = (u16*)alloc(2048 * 512 * 2);
    u16* WT_hhb   = (u16*)alloc(2048 * 512 * 2);
    u16* WprojTf  = (u16*)alloc(512 * 512 * 2);
    u16* WprojTb  = (u16*)alloc(512 * 512 * 2);
    u16* WprojAf  = (u16*)alloc(512 * 512 * 2);
    u16* WprojAb  = (u16*)alloc(512 * 512 * 2);
    u16* WT_lin   = (u16*)alloc((size_t)50304 * 512 * 2);
    float* xpf    = (float*)alloc((size_t)2048 * 2048 * 4);
    float* xpb    = (float*)alloc((size_t)2048 * 2048 * 4);
    float* Wc32f  = (float*)alloc((size_t)512 * 2048 * 4);
    float* Wc32b  = (float*)alloc((size_t)512 * 2048 * 4);
    u16* hpref    = (u16*)alloc((size_t)2048 * 512 * 2);
    u16* hpreb    = (u16*)alloc((size_t)2048 * 512 * 2);
    u16* hall     = (u16*)alloc((size_t)4096 * 512 * 2);
    u64* htag     = (u64*)alloc((size_t)2 * 2 * 4 * 256 * 8);

    zero_init<<<1, 256, 0, stream>>>(htag);
    gather_emb<<<2048, 256, 0, stream>>>(tokens, emb, xemb);

    transpose_cvt<<<dim3(64, 10), 256, 0, stream>>>(W_ih_f, WT_ihf, 300, 2048, 2048, 320);
    transpose_cvt<<<dim3(64, 10), 256, 0, stream>>>(W_ih_b, WT_ihb, 300, 2048, 2048, 320);
    transpose_cvt<<<dim3(64, 16), 256, 0, stream>>>(W_hh_f, WT_hhf, 512, 2048, 2048, 512);
    transpose_cvt<<<dim3(64, 16), 256, 0, stream>>>(W_hh_b, WT_hhb, 512, 2048, 2048, 512);
    transpose_cvt<<<dim3(16, 16), 256, 0, stream>>>(W_proj_f, WprojTf, 512, 512, 512, 512);
    transpose_cvt<<<dim3(16, 16), 256, 0, stream>>>(W_proj_b, WprojTb, 512, 512, 512, 512);
    transpose_cvt<<<dim3(1572, 16), 256, 0, stream>>>(W_lin, WT_lin, 512, 50257, 50304, 512);
    cvt_flat<<<512, 256, 0, stream>>>(W_proj_f, WprojAf, 512 * 512);
    cvt_flat<<<512, 256, 0, stream>>>(W_proj_b, WprojAb, 512 * 512);

    // xp = (emb gather) @ W_ih + b   (state_linearity bias folded in; bwd uses time-reversed rows)
    gemm_bf16<<<dim3(16, 16), 256, 0, stream>>>(xemb, WT_ihf, xpf, nullptr, b_f,
                                                2048, 2048, 320, 320, 320, 2048, 0, 0, 0);
    gemm_bf16<<<dim3(16, 16), 256, 0, stream>>>(xemb, WT_ihb, xpb, nullptr, b_b,
                                                2048, 2048, 320, 320, 320, 2048, 1, 0, 0);
    // Wc = W_proj @ W_hh
    gemm_bf16<<<dim3(16, 4), 256, 0, stream>>>(WprojAf, WT_hhf, Wc32f, nullptr, nullptr,
                                               512, 2048, 512, 512, 512, 2048, 0, 0, 0);
    gemm_bf16<<<dim3(16, 4), 256, 0, stream>>>(WprojAb, WT_hhb, Wc32b, nullptr, nullptr,
                                               512, 2048, 512, 512, 512, 2048, 0, 0, 0);

    lstm_rec<<<64, 256, 0, stream>>>(Wc32f, Wc32b, xpf, xpb, htag, hpref, hpreb);

    // h = h_pre @ W_proj  (bwd output rows time-reversed, offset 2048)
    gemm_bf16<<<dim3(4, 16), 256, 0, stream>>>(hpref, WprojTf, nullptr, hall, nullptr,
                                               2048, 512, 512, 512, 512, 512, 0, 0, 0);
    gemm_bf16<<<dim3(4, 16), 256, 0, stream>>>(hpreb, WprojTb, nullptr, hall, nullptr,
                                               2048, 512, 512, 512, 512, 512, 0, 1, 2048);
    // logits = h @ W_lin + b_lin
    gemm_bf16<<<dim3(393, 32), 256, 0, stream>>>(hall, WT_lin, out, nullptr, b_lin,
                                                 4096, 50257, 512, 512, 512, 50257, 0, 0, 0);
}

// Round 5
// 1792.999 us; speedup vs baseline: 3.1346x; 1.0370x over previous
//
#include <hip/hip_runtime.h>
#include <hip/hip_bf16.h>

typedef unsigned short u16;
typedef unsigned int u32;
typedef unsigned long long u64;
typedef short bf16x8 __attribute__((ext_vector_type(8)));
typedef float f32x4 __attribute__((ext_vector_type(4)));

// address-space casts for global_load_lds
#define AS1C(p) ((const __attribute__((address_space(1))) void*)(p))
#define AS3(p)  ((__attribute__((address_space(3))) void*)(p))

// ---------- helpers ----------
__device__ __forceinline__ u16 f2bf(float f) {
    union { float f; unsigned u; } v; v.f = f;
    unsigned x = v.u;
    unsigned r = (x + 0x7FFFu + ((x >> 16) & 1u)) >> 16;   // RNE
    return (u16)r;
}

// transpose+cvt tile job: in f32[R][C] -> out bf16[c][r], zero-pad OOB
__device__ __forceinline__ void tpose_dev(float (*tile)[33],
        const float* __restrict__ in, u16* __restrict__ out,
        int R, int C, int outR, int ldO, int bx, int by) {
    int c0 = bx * 32, r0 = by * 32;
    int tx = threadIdx.x & 31, ty = threadIdx.x >> 5;
#pragma unroll
    for (int yy = 0; yy < 4; ++yy) {
        int r = r0 + ty + yy * 8, cc = c0 + tx;
        tile[ty + yy * 8][tx] = (r < R && cc < C) ? in[(size_t)r * C + cc] : 0.f;
    }
    __syncthreads();
#pragma unroll
    for (int yy = 0; yy < 4; ++yy) {
        int c = c0 + ty + yy * 8, r = r0 + tx;
        if (c < outR && r < ldO) out[(size_t)c * ldO + r] = f2bf(tile[tx][ty + yy * 8]);
    }
}

// ---------- K1: fused prep (gather + all small transposes/cvts + htag zero) ----------
__global__ __launch_bounds__(256) void prep(
    const int* __restrict__ tokens, const float* __restrict__ emb, u16* __restrict__ xemb,
    const float* __restrict__ W_ih_f, u16* __restrict__ WT_ihf,
    const float* __restrict__ W_ih_b, u16* __restrict__ WT_ihb,
    const float* __restrict__ W_hh_f, u16* __restrict__ WT_hhf,
    const float* __restrict__ W_hh_b, u16* __restrict__ WT_hhb,
    const float* __restrict__ W_proj_f, u16* __restrict__ WprojTf,
    const float* __restrict__ W_proj_b, u16* __restrict__ WprojTb,
    u16* __restrict__ WprojAf, u16* __restrict__ WprojAb,
    u64* __restrict__ htag)
{
    __shared__ float tile[32][33];
    int bid = blockIdx.x;
    int tid = threadIdx.x;
    if (bid < 2048) {                       // embedding gather, K padded 300->320
        int tok = tokens[bid];
        const float* src = emb + (size_t)tok * 300;
        u16* dst = xemb + (size_t)bid * 320;
        int c = tid;
        if (c < 320) dst[c] = (c < 300) ? f2bf(src[c]) : (u16)0;
        c += 256;
        if (c < 320) dst[c] = (c < 300) ? f2bf(src[c]) : (u16)0;
        return;
    }
    bid -= 2048;
    if (bid < 640)  { tpose_dev(tile, W_ih_f, WT_ihf, 300, 2048, 2048, 320, bid % 64, bid / 64); return; }
    bid -= 640;
    if (bid < 640)  { tpose_dev(tile, W_ih_b, WT_ihb, 300, 2048, 2048, 320, bid % 64, bid / 64); return; }
    bid -= 640;
    if (bid < 1024) { tpose_dev(tile, W_hh_f, WT_hhf, 512, 2048, 2048, 512, bid % 64, bid / 64); return; }
    bid -= 1024;
    if (bid < 1024) { tpose_dev(tile, W_hh_b, WT_hhb, 512, 2048, 2048, 512, bid % 64, bid / 64); return; }
    bid -= 1024;
    if (bid < 256)  { tpose_dev(tile, W_proj_f, WprojTf, 512, 512, 512, 512, bid % 16, bid / 16); return; }
    bid -= 256;
    if (bid < 256)  { tpose_dev(tile, W_proj_b, WprojTb, 512, 512, 512, 512, bid % 16, bid / 16); return; }
    bid -= 256;
    if (bid < 512)  { int i = bid * 512 + tid; WprojAf[i] = f2bf(W_proj_f[i]); WprojAf[i + 256] = f2bf(W_proj_f[i + 256]); return; }
    bid -= 512;
    if (bid < 512)  { int i = bid * 512 + tid; WprojAb[i] = f2bf(W_proj_b[i]); WprojAb[i + 256] = f2bf(W_proj_b[i + 256]); return; }
    bid -= 512;
    // htag zero (1 block) — must run every call; harness does not re-poison
    for (int i = tid; i < 2 * 2 * 4 * 256; i += 256) htag[i] = 0ull;
}

// ---------- GEMM body: C[M,N] = A[M,K] @ BT[N,K]^T (+bias) ----------
// 128x128 tile, BK=32, m97 structure (global_load_lds dwordx4, src-side XOR pre-swizzle
// chunk^=(row&3) matched on ds_read_b128 — both-sides-or-neither).
struct GemmJob {
    const u16* A; const u16* BT; float* Cf; u16* Cb; const float* bias;
    int M, Nreal, K, ldA, ldB, ldC, arev, orev, orow_base;
};

__device__ __forceinline__ void gemm_body(const GemmJob& j) {
    __shared__ char As[8192];
    __shared__ char Bs[8192];
    const int tid = threadIdx.x;
    const int lane = tid & 63;
    const int wid = tid >> 6;
    const int wr = wid >> 1, wc = wid & 1;
    const int m0 = blockIdx.y * 128;
    const int n0 = blockIdx.x * 128;

    f32x4 zero4 = {0.f, 0.f, 0.f, 0.f};
    f32x4 acc[4][4];
#pragma unroll
    for (int i = 0; i < 4; ++i)
#pragma unroll
        for (int jx = 0; jx < 4; ++jx) acc[i][jx] = zero4;

    const int kIters = j.K >> 5;
    const int l15 = lane & 15, kg = lane >> 4;

    const int srow0 = wid * 32 + (lane >> 2);
    const int srow1 = srow0 + 16;
    const int c0 = (lane & 3) ^ (srow0 & 3);
    const int c1 = (lane & 3) ^ (srow1 & 3);
    int ar0 = m0 + srow0, ar1 = m0 + srow1;
    if (j.arev) {
        ar0 = (ar0 & ~511) | (511 - (ar0 & 511));
        ar1 = (ar1 & ~511) | (511 - (ar1 & 511));
    }
    const u16* ga0 = j.A + (size_t)ar0 * j.ldA + c0 * 8;
    const u16* ga1 = j.A + (size_t)ar1 * j.ldA + c1 * 8;
    const u16* gb0 = j.BT + (size_t)(n0 + srow0) * j.ldB + c0 * 8;
    const u16* gb1 = j.BT + (size_t)(n0 + srow1) * j.ldB + c1 * 8;
    char* ldsA0 = As + wid * 2048;
    char* ldsA1 = As + wid * 2048 + 1024;
    char* ldsB0 = Bs + wid * 2048;
    char* ldsB1 = Bs + wid * 2048 + 1024;

    for (int kt = 0; kt < kIters; ++kt) {
        const int k0 = kt * 32;
        __builtin_amdgcn_global_load_lds(AS1C(ga0 + k0), AS3(ldsA0), 16, 0, 0);
        __builtin_amdgcn_global_load_lds(AS1C(ga1 + k0), AS3(ldsA1), 16, 0, 0);
        __builtin_amdgcn_global_load_lds(AS1C(gb0 + k0), AS3(ldsB0), 16, 0, 0);
        __builtin_amdgcn_global_load_lds(AS1C(gb1 + k0), AS3(ldsB1), 16, 0, 0);
        __syncthreads();

        bf16x8 af[4], bfr[4];
#pragma unroll
        for (int mt = 0; mt < 4; ++mt) {
            int r = wr * 64 + mt * 16 + l15;
            af[mt] = *(const bf16x8*)(As + r * 64 + ((kg ^ (r & 3)) * 16));
        }
#pragma unroll
        for (int nt = 0; nt < 4; ++nt) {
            int r = wc * 64 + nt * 16 + l15;
            bfr[nt] = *(const bf16x8*)(Bs + r * 64 + ((kg ^ (r & 3)) * 16));
        }
#pragma unroll
        for (int mt = 0; mt < 4; ++mt)
#pragma unroll
            for (int nt = 0; nt < 4; ++nt)
                acc[mt][nt] = __builtin_amdgcn_mfma_f32_16x16x32_bf16(af[mt], bfr[nt], acc[mt][nt], 0, 0, 0);
        __syncthreads();
    }

#pragma unroll
    for (int nt = 0; nt < 4; ++nt) {
        int col = n0 + wc * 64 + nt * 16 + l15;
        float bv = (j.bias != nullptr && col < j.Nreal) ? j.bias[col] : 0.f;
#pragma unroll
        for (int mt = 0; mt < 4; ++mt) {
#pragma unroll
            for (int jx = 0; jx < 4; ++jx) {
                int m = m0 + wr * 64 + mt * 16 + kg * 4 + jx;
                int om = j.orev ? ((m & ~511) | (511 - (m & 511))) : m;
                om += j.orow_base;
                if (col < j.Nreal) {
                    float v = acc[mt][nt][jx] + bv;
                    if (j.Cf) j.Cf[(size_t)om * j.ldC + col] = v;
                    else      j.Cb[(size_t)om * j.ldC + col] = f2bf(v);
                }
            }
        }
    }
}

__global__ __launch_bounds__(256) void gemm_multi4(GemmJob j0, GemmJob j1, GemmJob j2, GemmJob j3) {
    GemmJob j = (blockIdx.z == 0) ? j0 : (blockIdx.z == 1) ? j1 : (blockIdx.z == 2) ? j2 : j3;
    if ((int)blockIdx.y * 128 >= j.M) return;
    gemm_body(j);
}
__global__ __launch_bounds__(256) void gemm_multi2(GemmJob j0, GemmJob j1) {
    GemmJob j = blockIdx.z ? j1 : j0;
    gemm_body(j);
}
__global__ __launch_bounds__(256) void gemm_one(GemmJob j0) { gemm_body(j0); }

// ---------- K5: persistent bidirectional LSTM recurrence (blocks 0..63), fence-free,
// + fused W_lin transpose (blocks 64..) running on otherwise-idle CUs in its shadow ----------
// Exchange via relaxed agent-scope (coherence-point) atomics; u64 = (tag)<<32 | 2x bf16 h.
// Poll = 4 batched global_load_dwordx2 sc0 sc1 + ONE vmcnt(0) (inline asm, dataflow-ordered).
// Parity double-buffer on t&1; publishing tag t+1 is safe because observing all tags==t
// proves every block finished reading the (t+1)&1 slot's tag t-1 values.
__global__ __launch_bounds__(256) void lstm_fused(
    const float* __restrict__ Wc_f, const float* __restrict__ Wc_b,
    const float* __restrict__ xp_f, const float* __restrict__ xp_b,
    u64* __restrict__ htag,
    u16* __restrict__ hpre_f, u16* __restrict__ hpre_b,
    const float* __restrict__ W_lin, u16* __restrict__ WT_lin)
{
    __shared__ float tile[32][33];
    __shared__ u16 hlds[4][520];
    __shared__ float gsum[4][4][16];
    __shared__ float cbuf[4][16];

    if (blockIdx.x >= 64) {   // W_lin transpose: 1572 x 16 tile jobs
        int job = blockIdx.x - 64;
        tpose_dev(tile, W_lin, WT_lin, 512, 50257, 50304, 512, job % 1572, job / 1572);
        return;
    }
    __builtin_amdgcn_s_setprio(1);   // favor rec waves over co-resident transpose waves

    const int tid = threadIdx.x;
    const int dir = blockIdx.x >> 5;
    const int blk = blockIdx.x & 31;
    const int lane = tid & 63;
    const int wid = tid >> 6;          // wave = gate
    const int l15 = lane & 15;
    const int kg = lane >> 4;

    const float* wcsrc = dir ? Wc_b : Wc_f;
    const float* xp    = dir ? xp_b : xp_f;
    u16* hpre          = dir ? hpre_b : hpre_f;
    u64* ht            = htag + (size_t)dir * 2 * 4 * 256;   // [slot][b][256 words]

    // Wc B-fragments in registers (one-time scattered read)
    bf16x8 wcf[16];
#pragma unroll
    for (int ks = 0; ks < 16; ++ks) {
        bf16x8 w;
#pragma unroll
        for (int e = 0; e < 8; ++e) {
            int k = ks * 32 + kg * 8 + e;
            w[e] = (short)f2bf(wcsrc[(size_t)k * 2048 + wid * 512 + blk * 16 + l15]);
        }
        wcf[ks] = w;
    }
    if (tid < 64) cbuf[tid >> 4][tid & 15] = 0.f;
    __syncthreads();

    const bf16x8 zero8 = {0, 0, 0, 0, 0, 0, 0, 0};
    const int b = tid >> 4, hu = tid & 15;

    for (int t = 0; t < 512; ++t) {
        // xp prefetch (independent of h) — issues before the spin
        float xpv0 = 0.f, xpv1 = 0.f, xpv2 = 0.f, xpv3 = 0.f;
        if (tid < 64) {
            const float* xr = xp + ((size_t)(b * 512 + t)) * 2048 + blk * 16 + hu;
            xpv0 = xr[0]; xpv1 = xr[512]; xpv2 = xr[1024]; xpv3 = xr[1536];
        }
        // cooperative tagged staging: thread tid owns word-column tid of all 4 batch rows
        {
            const u64* src = ht + (size_t)(t & 1) * 4 * 256;
            const u64* p0 = src + tid;
            const u64* p1 = src + 256 + tid;
            const u64* p2 = src + 512 + tid;
            const u64* p3 = src + 768 + tid;
            const u32 target = (u32)t;
            u64 w0, w1, w2, w3;
            for (;;) {
                asm volatile(
                    "global_load_dwordx2 %0, %4, off sc0 sc1\n\t"
                    "global_load_dwordx2 %1, %5, off sc0 sc1\n\t"
                    "global_load_dwordx2 %2, %6, off sc0 sc1\n\t"
                    "global_load_dwordx2 %3, %7, off sc0 sc1\n\t"
                    "s_waitcnt vmcnt(0)"
                    : "=&v"(w0), "=&v"(w1), "=&v"(w2), "=&v"(w3)
                    : "v"(p0), "v"(p1), "v"(p2), "v"(p3)
                    : "memory");
                if (((u32)(w0 >> 32) == target) & ((u32)(w1 >> 32) == target) &
                    ((u32)(w2 >> 32) == target) & ((u32)(w3 >> 32) == target)) break;
                __builtin_amdgcn_s_sleep(1);
            }
            asm volatile("" ::: "memory");
            *(u32*)&hlds[0][tid * 2] = (u32)w0;
            *(u32*)&hlds[1][tid * 2] = (u32)w1;
            *(u32*)&hlds[2][tid * 2] = (u32)w2;
            *(u32*)&hlds[3][tid * 2] = (u32)w3;
        }
        __syncthreads();   // SYNC_A: staging -> fragment reads (also protects gsum reuse)

        // p-slice for this wave's gate over K=512; 4 chains for shorter dep depth
        f32x4 a0 = {0,0,0,0}, a1 = {0,0,0,0}, a2 = {0,0,0,0}, a3 = {0,0,0,0};
#pragma unroll
        for (int ks = 0; ks < 16; ++ks) {
            bf16x8 a = zero8;
            if (l15 < 4) a = *(const bf16x8*)&hlds[l15][ks * 32 + kg * 8];
            switch (ks & 3) {
                case 0: a0 = __builtin_amdgcn_mfma_f32_16x16x32_bf16(a, wcf[ks], a0, 0, 0, 0); break;
                case 1: a1 = __builtin_amdgcn_mfma_f32_16x16x32_bf16(a, wcf[ks], a1, 0, 0, 0); break;
                case 2: a2 = __builtin_amdgcn_mfma_f32_16x16x32_bf16(a, wcf[ks], a2, 0, 0, 0); break;
                default: a3 = __builtin_amdgcn_mfma_f32_16x16x32_bf16(a, wcf[ks], a3, 0, 0, 0); break;
            }
        }
        f32x4 accs = (a0 + a1) + (a2 + a3);
        if (lane < 16) {
#pragma unroll
            for (int jx = 0; jx < 4; ++jx) gsum[wid][jx][lane] = accs[jx];
        }
        __syncthreads();   // SYNC_B: gsum -> gate math (also protects hlds reuse)

        if (tid < 64) {
            float pi = xpv0 + gsum[0][b][hu];
            float pf = xpv1 + gsum[1][b][hu];
            float pg = xpv2 + gsum[2][b][hu];
            float po = xpv3 + gsum[3][b][hu];
            float iv = 1.f / (1.f + expf(-pi));
            float fv = 1.f / (1.f + expf(-pf));
            float gv = tanhf(pg);
            float ov = 1.f / (1.f + expf(-po));
            float c2 = iv * gv + fv * cbuf[b][hu];
            cbuf[b][hu] = c2;
            u16 hpb = f2bf(ov * tanhf(c2));
            // publish FIRST (critical store), then the private hpre row
            unsigned v = hpb;
            unsigned nb = (unsigned)__shfl_down((int)v, 1);
            if ((tid & 1) == 0) {
                u32 packed = v | (nb << 16);
                u64 val = ((u64)(u32)(t + 1) << 32) | (u64)packed;
                size_t idx = (size_t)(((t + 1) & 1) * 4 + b) * 256 + blk * 8 + (hu >> 1);
                __hip_atomic_store(&ht[idx], val, __ATOMIC_RELAXED, __HIP_MEMORY_SCOPE_AGENT);
            }
            hpre[(size_t)(b * 512 + t) * 512 + blk * 16 + hu] = hpb;
        }
    }
}

// ---------- host ----------
extern "C" void kernel_launch(void* const* d_in, const int* in_sizes, int n_in,
                              void* d_out, int out_size, void* d_ws, size_t ws_size,
                              hipStream_t stream) {
    const int*   tokens   = (const int*)d_in[0];
    const float* emb      = (const float*)d_in[1];
    const float* W_ih_f   = (const float*)d_in[2];
    const float* W_hh_f   = (const float*)d_in[3];
    const float* b_f      = (const float*)d_in[4];
    const float* W_proj_f = (const float*)d_in[5];
    const float* W_ih_b   = (const float*)d_in[6];
    const float* W_hh_b   = (const float*)d_in[7];
    const float* b_b      = (const float*)d_in[8];
    const float* W_proj_b = (const float*)d_in[9];
    const float* W_lin    = (const float*)d_in[10];
    const float* b_lin    = (const float*)d_in[11];
    float* out = (float*)d_out;

    char* ws = (char*)d_ws;
    size_t off = 0;
    auto alloc = [&](size_t bytes) -> char* {
        char* p = ws + off;
        off = (off + bytes + 255) & ~(size_t)255;
        return p;
    };
    u16* xemb     = (u16*)alloc(2048 * 320 * 2);
    u16* WT_ihf   = (u16*)alloc(2048 * 320 * 2);
    u16* WT_ihb   = (u16*)alloc(2048 * 320 * 2);
    u16* WT_hhf   = (u16*)alloc(2048 * 512 * 2);
    u16* WT_hhb   = (u16*)alloc(2048 * 512 * 2);
    u16* WprojTf  = (u16*)alloc(512 * 512 * 2);
    u16* WprojTb  = (u16*)alloc(512 * 512 * 2);
    u16* WprojAf  = (u16*)alloc(512 * 512 * 2);
    u16* WprojAb  = (u16*)alloc(512 * 512 * 2);
    u16* WT_lin   = (u16*)alloc((size_t)50304 * 512 * 2);
    float* xpf    = (float*)alloc((size_t)2048 * 2048 * 4);
    float* xpb    = (float*)alloc((size_t)2048 * 2048 * 4);
    float* Wc32f  = (float*)alloc((size_t)512 * 2048 * 4);
    float* Wc32b  = (float*)alloc((size_t)512 * 2048 * 4);
    u16* hpref    = (u16*)alloc((size_t)2048 * 512 * 2);
    u16* hpreb    = (u16*)alloc((size_t)2048 * 512 * 2);
    u16* hall     = (u16*)alloc((size_t)4096 * 512 * 2);
    u64* htag     = (u64*)alloc((size_t)2 * 2 * 4 * 256 * 8);

    // 1) all prep in one launch (gather, 6 transposes, 2 cvts, htag zero)
    prep<<<6913, 256, 0, stream>>>(tokens, emb, xemb,
                                   W_ih_f, WT_ihf, W_ih_b, WT_ihb,
                                   W_hh_f, WT_hhf, W_hh_b, WT_hhb,
                                   W_proj_f, WprojTf, W_proj_b, WprojTb,
                                   WprojAf, WprojAb, htag);

    // 2) xp (fwd, bwd) + Wc (fwd, bwd) in one z=4 launch
    GemmJob jxf = {xemb, WT_ihf, xpf, nullptr, b_f, 2048, 2048, 320, 320, 320, 2048, 0, 0, 0};
    GemmJob jxb = {xemb, WT_ihb, xpb, nullptr, b_b, 2048, 2048, 320, 320, 320, 2048, 1, 0, 0};
    GemmJob jwf = {WprojAf, WT_hhf, Wc32f, nullptr, nullptr, 512, 2048, 512, 512, 512, 2048, 0, 0, 0};
    GemmJob jwb = {WprojAb, WT_hhb, Wc32b, nullptr, nullptr, 512, 2048, 512, 512, 512, 2048, 0, 0, 0};
    gemm_multi4<<<dim3(16, 16, 4), 256, 0, stream>>>(jxf, jxb, jwf, jwb);

    // 3) recurrence (blocks 0..63) + W_lin transpose (blocks 64..) in its shadow
    lstm_fused<<<64 + 1572 * 16, 256, 0, stream>>>(Wc32f, Wc32b, xpf, xpb, htag,
                                                   hpref, hpreb, W_lin, WT_lin);

    // 4) h = h_pre @ W_proj (bwd rows time-reversed, offset 2048), z=2
    GemmJob jpf = {hpref, WprojTf, nullptr, hall, nullptr, 2048, 512, 512, 512, 512, 512, 0, 0, 0};
    GemmJob jpb = {hpreb, WprojTb, nullptr, hall, nullptr, 2048, 512, 512, 512, 512, 512, 0, 1, 2048};
    gemm_multi2<<<dim3(4, 16, 2), 256, 0, stream>>>(jpf, jpb);

    // 5) logits = h @ W_lin + b_lin
    GemmJob jl = {hall, WT_lin, out, nullptr, b_lin, 4096, 50257, 512, 512, 512, 50257, 0, 0, 0};
    gemm_one<<<dim3(393, 32), 256, 0, stream>>>(jl);
}

// Round 6
// 1671.939 us; speedup vs baseline: 3.3615x; 1.0724x over previous
//
#include <hip/hip_runtime.h>
#include <hip/hip_bf16.h>

typedef unsigned short u16;
typedef unsigned int u32;
typedef unsigned long long u64;
typedef short bf16x8 __attribute__((ext_vector_type(8)));
typedef float f32x4 __attribute__((ext_vector_type(4)));

#define AS1C(p) ((const __attribute__((address_space(1))) void*)(p))
#define AS3(p)  ((__attribute__((address_space(3))) void*)(p))

__device__ __forceinline__ u16 f2bf(float f) {
    union { float f; unsigned u; } v; v.f = f;
    unsigned x = v.u;
    unsigned r = (x + 0x7FFFu + ((x >> 16) & 1u)) >> 16;   // RNE
    return (u16)r;
}
__device__ __forceinline__ void st_atomic_u32(u32* p, u32 v) {
    __hip_atomic_store(p, v, __ATOMIC_RELAXED, __HIP_MEMORY_SCOPE_AGENT);
}
__device__ __forceinline__ u32 ld_atomic_u32(const u32* p) {
    return __hip_atomic_load(p, __ATOMIC_RELAXED, __HIP_MEMORY_SCOPE_AGENT);
}

// transpose+cvt tile: in f32[R][C] -> out bf16[c][r]; atomicStore -> coherence-point u32 pairs
__device__ __forceinline__ void tpose_dev(float (*tile)[33],
        const float* __restrict__ in, u16* __restrict__ out,
        int R, int C, int outR, int ldO, int bx, int by, int atomicStore) {
    int c0 = bx * 32, r0 = by * 32;
    int tx = threadIdx.x & 31, ty = threadIdx.x >> 5;
#pragma unroll
    for (int yy = 0; yy < 4; ++yy) {
        int r = r0 + ty + yy * 8, cc = c0 + tx;
        tile[ty + yy * 8][tx] = (r < R && cc < C) ? in[(size_t)r * C + cc] : 0.f;
    }
    __syncthreads();
#pragma unroll
    for (int yy = 0; yy < 4; ++yy) {
        int c = c0 + ty + yy * 8, r = r0 + tx;
        float v = tile[tx][ty + yy * 8];
        if (atomicStore) {
            float pv = __shfl_down(v, 1);
            if ((tx & 1) == 0 && c < outR && r < ldO)
                st_atomic_u32((u32*)&out[(size_t)c * ldO + r], (u32)f2bf(v) | ((u32)f2bf(pv) << 16));
        } else {
            if (c < outR && r < ldO) out[(size_t)c * ldO + r] = f2bf(v);
        }
    }
    __syncthreads();   // tile reusable by caller's next iteration
}

// ---------- K1: fused prep (gather + small transposes/cvts + htag/ctr zero) ----------
__global__ __launch_bounds__(256) void prep(
    const int* __restrict__ tokens, const float* __restrict__ emb, u16* __restrict__ xemb,
    const float* __restrict__ W_ih_f, u16* __restrict__ WT_ihf,
    const float* __restrict__ W_ih_b, u16* __restrict__ WT_ihb,
    const float* __restrict__ W_hh_f, u16* __restrict__ WT_hhf,
    const float* __restrict__ W_hh_b, u16* __restrict__ WT_hhb,
    const float* __restrict__ W_proj_f, u16* __restrict__ WprojTf,
    const float* __restrict__ W_proj_b, u16* __restrict__ WprojTb,
    u16* __restrict__ WprojAf, u16* __restrict__ WprojAb,
    u64* __restrict__ htag, u32* __restrict__ ctr)
{
    __shared__ float tile[32][33];
    int bid = blockIdx.x;
    int tid = threadIdx.x;
    if (bid < 2048) {
        int tok = tokens[bid];
        const float* src = emb + (size_t)tok * 300;
        u16* dst = xemb + (size_t)bid * 320;
        int c = tid;
        if (c < 320) dst[c] = (c < 300) ? f2bf(src[c]) : (u16)0;
        c += 256;
        if (c < 320) dst[c] = (c < 300) ? f2bf(src[c]) : (u16)0;
        return;
    }
    bid -= 2048;
    if (bid < 640)  { tpose_dev(tile, W_ih_f, WT_ihf, 300, 2048, 2048, 320, bid % 64, bid / 64, 0); return; }
    bid -= 640;
    if (bid < 640)  { tpose_dev(tile, W_ih_b, WT_ihb, 300, 2048, 2048, 320, bid % 64, bid / 64, 0); return; }
    bid -= 640;
    if (bid < 1024) { tpose_dev(tile, W_hh_f, WT_hhf, 512, 2048, 2048, 512, bid % 64, bid / 64, 0); return; }
    bid -= 1024;
    if (bid < 1024) { tpose_dev(tile, W_hh_b, WT_hhb, 512, 2048, 2048, 512, bid % 64, bid / 64, 0); return; }
    bid -= 1024;
    if (bid < 256)  { tpose_dev(tile, W_proj_f, WprojTf, 512, 512, 512, 512, bid % 16, bid / 16, 0); return; }
    bid -= 256;
    if (bid < 256)  { tpose_dev(tile, W_proj_b, WprojTb, 512, 512, 512, 512, bid % 16, bid / 16, 0); return; }
    bid -= 256;
    if (bid < 512)  { int i = bid * 512 + tid; WprojAf[i] = f2bf(W_proj_f[i]); WprojAf[i + 256] = f2bf(W_proj_f[i + 256]); return; }
    bid -= 512;
    if (bid < 512)  { int i = bid * 512 + tid; WprojAb[i] = f2bf(W_proj_b[i]); WprojAb[i + 256] = f2bf(W_proj_b[i + 256]); return; }
    // zero htag + counters — must run every call (harness does not re-poison)
    for (int i = tid; i < 2 * 2 * 4 * 256; i += 256) htag[i] = 0ull;
    if (tid < 64) ctr[tid] = 0;
}

// ---------- GEMM body: C[M0+.., N0+..] tile of A[M,K] @ BT[N,K]^T (+bias) ----------
// 128x128 tile, BK=32, m97 structure (global_load_lds dwordx4, src-side XOR pre-swizzle
// chunk^=(row&3) matched on swizzled ds_read_b128 — both-sides-or-neither).
struct GemmJob {
    const u16* A; const u16* BT; float* Cf; u16* Cb; const float* bias;
    int M, Nreal, K, ldA, ldB, ldC, arev, orev, orow_base;
};

__device__ __forceinline__ void gemm_body(const GemmJob& j, int m0, int n0,
                                          char* As, char* Bs, int atomicCb) {
    const int tid = threadIdx.x;
    const int lane = tid & 63;
    const int wid = tid >> 6;
    const int wr = wid >> 1, wc = wid & 1;

    f32x4 zero4 = {0.f, 0.f, 0.f, 0.f};
    f32x4 acc[4][4];
#pragma unroll
    for (int i = 0; i < 4; ++i)
#pragma unroll
        for (int jx = 0; jx < 4; ++jx) acc[i][jx] = zero4;

    const int kIters = j.K >> 5;
    const int l15 = lane & 15, kg = lane >> 4;

    const int srow0 = wid * 32 + (lane >> 2);
    const int srow1 = srow0 + 16;
    const int c0 = (lane & 3) ^ (srow0 & 3);
    const int c1 = (lane & 3) ^ (srow1 & 3);
    int ar0 = m0 + srow0, ar1 = m0 + srow1;
    if (j.arev) {
        ar0 = (ar0 & ~511) | (511 - (ar0 & 511));
        ar1 = (ar1 & ~511) | (511 - (ar1 & 511));
    }
    const u16* ga0 = j.A + (size_t)ar0 * j.ldA + c0 * 8;
    const u16* ga1 = j.A + (size_t)ar1 * j.ldA + c1 * 8;
    const u16* gb0 = j.BT + (size_t)(n0 + srow0) * j.ldB + c0 * 8;
    const u16* gb1 = j.BT + (size_t)(n0 + srow1) * j.ldB + c1 * 8;
    char* ldsA0 = As + wid * 2048;
    char* ldsA1 = As + wid * 2048 + 1024;
    char* ldsB0 = Bs + wid * 2048;
    char* ldsB1 = Bs + wid * 2048 + 1024;

    for (int kt = 0; kt < kIters; ++kt) {
        const int k0 = kt * 32;
        __builtin_amdgcn_global_load_lds(AS1C(ga0 + k0), AS3(ldsA0), 16, 0, 0);
        __builtin_amdgcn_global_load_lds(AS1C(ga1 + k0), AS3(ldsA1), 16, 0, 0);
        __builtin_amdgcn_global_load_lds(AS1C(gb0 + k0), AS3(ldsB0), 16, 0, 0);
        __builtin_amdgcn_global_load_lds(AS1C(gb1 + k0), AS3(ldsB1), 16, 0, 0);
        __syncthreads();

        bf16x8 af[4], bfr[4];
#pragma unroll
        for (int mt = 0; mt < 4; ++mt) {
            int r = wr * 64 + mt * 16 + l15;
            af[mt] = *(const bf16x8*)(As + r * 64 + ((kg ^ (r & 3)) * 16));
        }
#pragma unroll
        for (int nt = 0; nt < 4; ++nt) {
            int r = wc * 64 + nt * 16 + l15;
            bfr[nt] = *(const bf16x8*)(Bs + r * 64 + ((kg ^ (r & 3)) * 16));
        }
#pragma unroll
        for (int mt = 0; mt < 4; ++mt)
#pragma unroll
            for (int nt = 0; nt < 4; ++nt)
                acc[mt][nt] = __builtin_amdgcn_mfma_f32_16x16x32_bf16(af[mt], bfr[nt], acc[mt][nt], 0, 0, 0);
        __syncthreads();
    }

#pragma unroll
    for (int nt = 0; nt < 4; ++nt) {
        int col = n0 + wc * 64 + nt * 16 + l15;
        float bv = (j.bias != nullptr && col < j.Nreal) ? j.bias[col] : 0.f;
#pragma unroll
        for (int mt = 0; mt < 4; ++mt) {
#pragma unroll
            for (int jx = 0; jx < 4; ++jx) {
                int m = m0 + wr * 64 + mt * 16 + kg * 4 + jx;
                int om = j.orev ? ((m & ~511) | (511 - (m & 511))) : m;
                om += j.orow_base;
                float v = acc[mt][nt][jx] + bv;
                if (atomicCb) {
                    float pv = __shfl_down(v, 1);
                    if ((l15 & 1) == 0 && col < j.Nreal)
                        st_atomic_u32((u32*)(j.Cb + (size_t)om * j.ldC + col),
                                      (u32)f2bf(v) | ((u32)f2bf(pv) << 16));
                } else if (col < j.Nreal) {
                    if (j.Cf) j.Cf[(size_t)om * j.ldC + col] = v;
                    else      j.Cb[(size_t)om * j.ldC + col] = f2bf(v);
                }
            }
        }
    }
}

__global__ __launch_bounds__(256) void gemm_multi4(GemmJob j0, GemmJob j1, GemmJob j2, GemmJob j3) {
    __shared__ char pool[16384];
    GemmJob j = (blockIdx.z == 0) ? j0 : (blockIdx.z == 1) ? j1 : (blockIdx.z == 2) ? j2 : j3;
    if ((int)blockIdx.y * 128 >= j.M) return;
    gemm_body(j, blockIdx.y * 128, blockIdx.x * 128, pool, pool + 8192, 0);
}

// ---------- K5: persistent LSTM recurrence + chased transpose/proj/logits mega-kernel ----------
// blocks 0..63: rec (dir=bid>>5, blk=bid&31 owns 16 hu). Fence-free htag exchange (R3 protocol).
// blocks 64..1635: WT_lin transpose strips (atomic u32 stores) -> ctr[0] (target 1572)
// blocks 1636..1763: proj chasers: wait rec chunk -> hall tile (atomic) -> ctr[16+band] (target 4)
// blocks 1764..14339: logits chasers: wait ctr[0] & ctr[16+band] -> out tile (plain f32 stores)
// Same-dispatch cross-XCD edges all use coherence-point u32 atomics + vmcnt(0)-then-counter.
// Liveness: waits only target lower blockIdx; rec blocks resident from dispatch start.
__global__ __launch_bounds__(256) void lstm_fused(
    const float* __restrict__ Wc_f, const float* __restrict__ Wc_b,
    const float* __restrict__ xp_f, const float* __restrict__ xp_b,
    u64* __restrict__ htag,
    u16* __restrict__ hpre_f, u16* __restrict__ hpre_b,
    const float* __restrict__ W_lin, u16* __restrict__ WT_lin,
    const u16* __restrict__ WprojTf, const u16* __restrict__ WprojTb,
    u16* __restrict__ hall, const float* __restrict__ b_lin,
    float* __restrict__ out, u32* __restrict__ ctr)
{
    __shared__ char pool[16640];
    const int tid = threadIdx.x;
    int bid = blockIdx.x;

    if (bid >= 64) {
        bid -= 64;
        if (bid < 1572) {   // WT_lin transpose strip: 16 row-tiles of 32-col strip
            float (*tile)[33] = (float(*)[33])pool;
            for (int by = 0; by < 16; ++by)
                tpose_dev(tile, W_lin, WT_lin, 512, 50257, 50304, 512, bid, by, 1);
            asm volatile("s_waitcnt vmcnt(0)" ::: "memory");
            __syncthreads();
            if (tid == 0) __hip_atomic_fetch_add(&ctr[0], 1u, __ATOMIC_RELAXED, __HIP_MEMORY_SCOPE_AGENT);
            return;
        }
        bid -= 1572;
        if (bid < 128) {    // proj chaser: hall tile = hpre @ W_proj
            int dir = bid >> 6, r = bid & 63, y = r >> 2, x = r & 3;
            int m0 = y * 128, n0 = x * 128;
            if (tid == 0) {
                while (ld_atomic_u32(&ctr[8 + dir * 4 + (y & 3)]) < 32u) __builtin_amdgcn_s_sleep(16);
            }
            __syncthreads();
            GemmJob j = { dir ? hpre_b : hpre_f, dir ? WprojTb : WprojTf, nullptr, hall, nullptr,
                          2048, 512, 512, 512, 512, 512, 0, dir ? 1 : 0, dir ? 2048 : 0 };
            gemm_body(j, m0, n0, pool, pool + 8192, 1);
            asm volatile("s_waitcnt vmcnt(0)" ::: "memory");
            __syncthreads();
            if (tid == 0) {
                int obrow = j.orow_base + (j.orev ? ((m0 & ~511) | (511 - ((m0 + 127) & 511))) : m0);
                __hip_atomic_fetch_add(&ctr[16 + (obrow >> 7)], 1u, __ATOMIC_RELAXED, __HIP_MEMORY_SCOPE_AGENT);
            }
            return;
        }
        bid -= 128;
        {                   // logits chaser, ordered by availability chunk
            int cid = bid / (393 * 8), rr = bid % (393 * 8), bi = rr / 393, x = rr % 393;
            int band = (bi < 4) ? (bi * 4 + cid) : (16 + (bi - 4) * 4 + (3 - cid));
            if (tid == 0) {
                while (ld_atomic_u32(&ctr[0]) < 1572u) __builtin_amdgcn_s_sleep(32);
                while (ld_atomic_u32(&ctr[16 + band]) < 4u) __builtin_amdgcn_s_sleep(32);
            }
            __syncthreads();
            GemmJob j = { hall, WT_lin, out, nullptr, b_lin,
                          4096, 50257, 512, 512, 512, 50257, 0, 0, 0 };
            gemm_body(j, band * 128, x * 128, pool, pool + 8192, 0);
            return;
        }
    }

    // ---------------- rec block ----------------
    __builtin_amdgcn_s_setprio(1);
    u16 (*hlds)[520] = (u16(*)[520])pool;                     // 4160 B
    float (*gsum)[4][16] = (float(*)[4][16])(pool + 4160);    // 1024 B
    float (*cbuf)[16] = (float(*)[16])(pool + 5184);          // 256 B

    const int dir = blockIdx.x >> 5;
    const int blk = blockIdx.x & 31;
    const int lane = tid & 63;
    const int wid = tid >> 6;          // wave = gate
    const int l15 = lane & 15;
    const int kg = lane >> 4;

    const float* wcsrc = dir ? Wc_b : Wc_f;
    const float* xp    = dir ? xp_b : xp_f;
    u16* hpre          = dir ? hpre_b : hpre_f;
    u64* ht            = htag + (size_t)dir * 2 * 4 * 256;

    bf16x8 wcf[16];
#pragma unroll
    for (int ks = 0; ks < 16; ++ks) {
        bf16x8 w;
#pragma unroll
        for (int e = 0; e < 8; ++e) {
            int k = ks * 32 + kg * 8 + e;
            w[e] = (short)f2bf(wcsrc[(size_t)k * 2048 + wid * 512 + blk * 16 + l15]);
        }
        wcf[ks] = w;
    }
    if (tid < 64) cbuf[tid >> 4][tid & 15] = 0.f;
    __syncthreads();

    const bf16x8 zero8 = {0, 0, 0, 0, 0, 0, 0, 0};
    const int b = tid >> 4, hu = tid & 15;

    for (int t = 0; t < 512; ++t) {
        float xpv0 = 0.f, xpv1 = 0.f, xpv2 = 0.f, xpv3 = 0.f;
        if (tid < 64) {
            const float* xr = xp + ((size_t)(b * 512 + t)) * 2048 + blk * 16 + hu;
            xpv0 = xr[0]; xpv1 = xr[512]; xpv2 = xr[1024]; xpv3 = xr[1536];
        }
        {   // batched tagged poll (data+flag in the same u64 words)
            const u64* src = ht + (size_t)(t & 1) * 4 * 256;
            const u64* p0 = src + tid;
            const u64* p1 = src + 256 + tid;
            const u64* p2 = src + 512 + tid;
            const u64* p3 = src + 768 + tid;
            const u32 target = (u32)t;
            u64 w0, w1, w2, w3;
            for (;;) {
                asm volatile(
                    "global_load_dwordx2 %0, %4, off sc0 sc1\n\t"
                    "global_load_dwordx2 %1, %5, off sc0 sc1\n\t"
                    "global_load_dwordx2 %2, %6, off sc0 sc1\n\t"
                    "global_load_dwordx2 %3, %7, off sc0 sc1\n\t"
                    "s_waitcnt vmcnt(0)"
                    : "=&v"(w0), "=&v"(w1), "=&v"(w2), "=&v"(w3)
                    : "v"(p0), "v"(p1), "v"(p2), "v"(p3)
                    : "memory");
                if (((u32)(w0 >> 32) == target) & ((u32)(w1 >> 32) == target) &
                    ((u32)(w2 >> 32) == target) & ((u32)(w3 >> 32) == target)) break;
                __builtin_amdgcn_s_sleep(1);
            }
            asm volatile("" ::: "memory");
            *(u32*)&hlds[0][tid * 2] = (u32)w0;
            *(u32*)&hlds[1][tid * 2] = (u32)w1;
            *(u32*)&hlds[2][tid * 2] = (u32)w2;
            *(u32*)&hlds[3][tid * 2] = (u32)w3;
        }
        __syncthreads();   // SYNC_A

        f32x4 a0 = {0,0,0,0}, a1 = {0,0,0,0}, a2 = {0,0,0,0}, a3 = {0,0,0,0};
#pragma unroll
        for (int ks = 0; ks < 16; ++ks) {
            bf16x8 a = zero8;
            if (l15 < 4) a = *(const bf16x8*)&hlds[l15][ks * 32 + kg * 8];
            switch (ks & 3) {
                case 0: a0 = __builtin_amdgcn_mfma_f32_16x16x32_bf16(a, wcf[ks], a0, 0, 0, 0); break;
                case 1: a1 = __builtin_amdgcn_mfma_f32_16x16x32_bf16(a, wcf[ks], a1, 0, 0, 0); break;
                case 2: a2 = __builtin_amdgcn_mfma_f32_16x16x32_bf16(a, wcf[ks], a2, 0, 0, 0); break;
                default: a3 = __builtin_amdgcn_mfma_f32_16x16x32_bf16(a, wcf[ks], a3, 0, 0, 0); break;
            }
        }
        f32x4 accs = (a0 + a1) + (a2 + a3);
        if (lane < 16) {
#pragma unroll
            for (int jx = 0; jx < 4; ++jx) gsum[wid][jx][lane] = accs[jx];
        }
        __syncthreads();   // SYNC_B

        if (tid < 64) {
            float pi = xpv0 + gsum[0][b][hu];
            float pf = xpv1 + gsum[1][b][hu];
            float pg = xpv2 + gsum[2][b][hu];
            float po = xpv3 + gsum[3][b][hu];
            float iv = 1.f / (1.f + expf(-pi));
            float fv = 1.f / (1.f + expf(-pf));
            float gv = tanhf(pg);
            float ov = 1.f / (1.f + expf(-po));
            float c2 = iv * gv + fv * cbuf[b][hu];
            cbuf[b][hu] = c2;
            u16 hpb = f2bf(ov * tanhf(c2));
            unsigned v = hpb;
            unsigned nb = (unsigned)__shfl_down((int)v, 1);
            if ((tid & 1) == 0) {
                u32 packed = v | (nb << 16);
                u64 val = ((u64)(u32)(t + 1) << 32) | (u64)packed;
                size_t idx = (size_t)(((t + 1) & 1) * 4 + b) * 256 + blk * 8 + (hu >> 1);
                __hip_atomic_store(&ht[idx], val, __ATOMIC_RELAXED, __HIP_MEMORY_SCOPE_AGENT);
                // hpre must be coherence-point visible to same-dispatch proj chasers
                st_atomic_u32((u32*)&hpre[(size_t)(b * 512 + t) * 512 + blk * 16 + hu], packed);
            }
        }
        if ((t & 127) == 127) {   // chunk boundary: drain wave-0 stores, then publish progress
            if (tid < 64) { asm volatile("s_waitcnt vmcnt(0)" ::: "memory"); }
            if (tid == 0)
                __hip_atomic_fetch_add(&ctr[8 + dir * 4 + (t >> 7)], 1u,
                                       __ATOMIC_RELAXED, __HIP_MEMORY_SCOPE_AGENT);
        }
    }
}

// ---------- host ----------
extern "C" void kernel_launch(void* const* d_in, const int* in_sizes, int n_in,
                              void* d_out, int out_size, void* d_ws, size_t ws_size,
                              hipStream_t stream) {
    const int*   tokens   = (const int*)d_in[0];
    const float* emb      = (const float*)d_in[1];
    const float* W_ih_f   = (const float*)d_in[2];
    const float* W_hh_f   = (const float*)d_in[3];
    const float* b_f      = (const float*)d_in[4];
    const float* W_proj_f = (const float*)d_in[5];
    const float* W_ih_b   = (const float*)d_in[6];
    const float* W_hh_b   = (const float*)d_in[7];
    const float* b_b      = (const float*)d_in[8];
    const float* W_proj_b = (const float*)d_in[9];
    const float* W_lin    = (const float*)d_in[10];
    const float* b_lin    = (const float*)d_in[11];
    float* out = (float*)d_out;

    char* ws = (char*)d_ws;
    size_t off = 0;
    auto alloc = [&](size_t bytes) -> char* {
        char* p = ws + off;
        off = (off + bytes + 255) & ~(size_t)255;
        return p;
    };
    u16* xemb     = (u16*)alloc(2048 * 320 * 2);
    u16* WT_ihf   = (u16*)alloc(2048 * 320 * 2);
    u16* WT_ihb   = (u16*)alloc(2048 * 320 * 2);
    u16* WT_hhf   = (u16*)alloc(2048 * 512 * 2);
    u16* WT_hhb   = (u16*)alloc(2048 * 512 * 2);
    u16* WprojTf  = (u16*)alloc(512 * 512 * 2);
    u16* WprojTb  = (u16*)alloc(512 * 512 * 2);
    u16* WprojAf  = (u16*)alloc(512 * 512 * 2);
    u16* WprojAb  = (u16*)alloc(512 * 512 * 2);
    u16* WT_lin   = (u16*)alloc((size_t)50304 * 512 * 2);
    float* xpf    = (float*)alloc((size_t)2048 * 2048 * 4);
    float* xpb    = (float*)alloc((size_t)2048 * 2048 * 4);
    float* Wc32f  = (float*)alloc((size_t)512 * 2048 * 4);
    float* Wc32b  = (float*)alloc((size_t)512 * 2048 * 4);
    u16* hpref    = (u16*)alloc((size_t)2048 * 512 * 2);
    u16* hpreb    = (u16*)alloc((size_t)2048 * 512 * 2);
    u16* hall     = (u16*)alloc((size_t)4096 * 512 * 2);
    u64* htag     = (u64*)alloc((size_t)2 * 2 * 4 * 256 * 8);
    u32* ctr      = (u32*)alloc(64 * 4);

    // 1) all prep in one launch
    prep<<<6913, 256, 0, stream>>>(tokens, emb, xemb,
                                   W_ih_f, WT_ihf, W_ih_b, WT_ihb,
                                   W_hh_f, WT_hhf, W_hh_b, WT_hhb,
                                   W_proj_f, WprojTf, W_proj_b, WprojTb,
                                   WprojAf, WprojAb, htag, ctr);

    // 2) xp (fwd, bwd) + Wc (fwd, bwd) in one z=4 launch
    GemmJob jxf = {xemb, WT_ihf, xpf, nullptr, b_f, 2048, 2048, 320, 320, 320, 2048, 0, 0, 0};
    GemmJob jxb = {xemb, WT_ihb, xpb, nullptr, b_b, 2048, 2048, 320, 320, 320, 2048, 1, 0, 0};
    GemmJob jwf = {WprojAf, WT_hhf, Wc32f, nullptr, nullptr, 512, 2048, 512, 512, 512, 2048, 0, 0, 0};
    GemmJob jwb = {WprojAb, WT_hhb, Wc32b, nullptr, nullptr, 512, 2048, 512, 512, 512, 2048, 0, 0, 0};
    gemm_multi4<<<dim3(16, 16, 4), 256, 0, stream>>>(jxf, jxb, jwf, jwb);

    // 3) mega-kernel: rec + WT_lin transpose + proj chasers + logits chasers
    lstm_fused<<<64 + 1572 + 128 + 12576, 256, 0, stream>>>(
        Wc32f, Wc32b, xpf, xpb, htag, hpref, hpreb,
        W_lin, WT_lin, WprojTf, WprojTb, hall, b_lin, out, ctr);
}

// Round 7
// 1663.154 us; speedup vs baseline: 3.3793x; 1.0053x over previous
//
#include <hip/hip_runtime.h>
#include <hip/hip_bf16.h>

typedef unsigned short u16;
typedef unsigned int u32;
typedef unsigned long long u64;
typedef short bf16x8 __attribute__((ext_vector_type(8)));
typedef float f32x4 __attribute__((ext_vector_type(4)));

#define AS1C(p) ((const __attribute__((address_space(1))) void*)(p))
#define AS3(p)  ((__attribute__((address_space(3))) void*)(p))

__device__ __forceinline__ u16 f2bf(float f) {
    union { float f; unsigned u; } v; v.f = f;
    unsigned x = v.u;
    unsigned r = (x + 0x7FFFu + ((x >> 16) & 1u)) >> 16;   // RNE
    return (u16)r;
}
__device__ __forceinline__ void st_atomic_u32(u32* p, u32 v) {
    __hip_atomic_store(p, v, __ATOMIC_RELAXED, __HIP_MEMORY_SCOPE_AGENT);
}
__device__ __forceinline__ u32 ld_atomic_u32(const u32* p) {
    return __hip_atomic_load(p, __ATOMIC_RELAXED, __HIP_MEMORY_SCOPE_AGENT);
}

// transpose+cvt tile: in f32[R][C] -> out bf16[c][r]; atomicStore -> coherence-point u32 pairs
__device__ __forceinline__ void tpose_dev(float (*tile)[33],
        const float* __restrict__ in, u16* __restrict__ out,
        int R, int C, int outR, int ldO, int bx, int by, int atomicStore) {
    int c0 = bx * 32, r0 = by * 32;
    int tx = threadIdx.x & 31, ty = threadIdx.x >> 5;
#pragma unroll
    for (int yy = 0; yy < 4; ++yy) {
        int r = r0 + ty + yy * 8, cc = c0 + tx;
        tile[ty + yy * 8][tx] = (r < R && cc < C) ? in[(size_t)r * C + cc] : 0.f;
    }
    __syncthreads();
#pragma unroll
    for (int yy = 0; yy < 4; ++yy) {
        int c = c0 + ty + yy * 8, r = r0 + tx;
        float v = tile[tx][ty + yy * 8];
        if (atomicStore) {
            float pv = __shfl_down(v, 1);
            if ((tx & 1) == 0 && c < outR && r < ldO)
                st_atomic_u32((u32*)&out[(size_t)c * ldO + r], (u32)f2bf(v) | ((u32)f2bf(pv) << 16));
        } else {
            if (c < outR && r < ldO) out[(size_t)c * ldO + r] = f2bf(v);
        }
    }
    __syncthreads();   // tile reusable by caller's next iteration
}

// ---------- K1: fused prep (gather + ALL transposes incl. W_lin + cvts + htag/ctr zero) ----------
// W_lin transpose lives here (plain stores): the prep->mega kernel boundary provides
// cross-XCD visibility for free, removing 12.9M coherence-point atomics + the global
// ctr[0] spin from the mega kernel (R6's contention source).
__global__ __launch_bounds__(256) void prep(
    const int* __restrict__ tokens, const float* __restrict__ emb, u16* __restrict__ xemb,
    const float* __restrict__ W_ih_f, u16* __restrict__ WT_ihf,
    const float* __restrict__ W_ih_b, u16* __restrict__ WT_ihb,
    const float* __restrict__ W_hh_f, u16* __restrict__ WT_hhf,
    const float* __restrict__ W_hh_b, u16* __restrict__ WT_hhb,
    const float* __restrict__ W_proj_f, u16* __restrict__ WprojTf,
    const float* __restrict__ W_proj_b, u16* __restrict__ WprojTb,
    u16* __restrict__ WprojAf, u16* __restrict__ WprojAb,
    const float* __restrict__ W_lin, u16* __restrict__ WT_lin,
    u64* __restrict__ htag, u32* __restrict__ ctr)
{
    __shared__ float tile[32][33];
    int bid = blockIdx.x;
    int tid = threadIdx.x;
    if (bid < 2048) {
        int tok = tokens[bid];
        const float* src = emb + (size_t)tok * 300;
        u16* dst = xemb + (size_t)bid * 320;
        int c = tid;
        if (c < 320) dst[c] = (c < 300) ? f2bf(src[c]) : (u16)0;
        c += 256;
        if (c < 320) dst[c] = (c < 300) ? f2bf(src[c]) : (u16)0;
        return;
    }
    bid -= 2048;
    if (bid < 640)  { tpose_dev(tile, W_ih_f, WT_ihf, 300, 2048, 2048, 320, bid % 64, bid / 64, 0); return; }
    bid -= 640;
    if (bid < 640)  { tpose_dev(tile, W_ih_b, WT_ihb, 300, 2048, 2048, 320, bid % 64, bid / 64, 0); return; }
    bid -= 640;
    if (bid < 1024) { tpose_dev(tile, W_hh_f, WT_hhf, 512, 2048, 2048, 512, bid % 64, bid / 64, 0); return; }
    bid -= 1024;
    if (bid < 1024) { tpose_dev(tile, W_hh_b, WT_hhb, 512, 2048, 2048, 512, bid % 64, bid / 64, 0); return; }
    bid -= 1024;
    if (bid < 256)  { tpose_dev(tile, W_proj_f, WprojTf, 512, 512, 512, 512, bid % 16, bid / 16, 0); return; }
    bid -= 256;
    if (bid < 256)  { tpose_dev(tile, W_proj_b, WprojTb, 512, 512, 512, 512, bid % 16, bid / 16, 0); return; }
    bid -= 256;
    if (bid < 512)  { int i = bid * 512 + tid; WprojAf[i] = f2bf(W_proj_f[i]); WprojAf[i + 256] = f2bf(W_proj_f[i + 256]); return; }
    bid -= 512;
    if (bid < 512)  { int i = bid * 512 + tid; WprojAb[i] = f2bf(W_proj_b[i]); WprojAb[i + 256] = f2bf(W_proj_b[i + 256]); return; }
    bid -= 512;
    if (bid < 25152) { tpose_dev(tile, W_lin, WT_lin, 512, 50257, 50304, 512, bid % 1572, bid / 1572, 0); return; }
    // zero htag + counters — must run every call (harness does not re-poison)
    for (int i = tid; i < 2 * 2 * 4 * 256; i += 256) htag[i] = 0ull;
    if (tid < 64) ctr[tid] = 0;
}

// ---------- GEMM body: C[M0+.., N0+..] tile of A[M,K] @ BT[N,K]^T (+bias) ----------
// 128x128 tile, BK=32, m97 structure (global_load_lds dwordx4, src-side XOR pre-swizzle
// chunk^=(row&3) matched on swizzled ds_read_b128 — both-sides-or-neither).
struct GemmJob {
    const u16* A; const u16* BT; float* Cf; u16* Cb; const float* bias;
    int M, Nreal, K, ldA, ldB, ldC, arev, orev, orow_base;
};

__device__ __forceinline__ void gemm_body(const GemmJob& j, int m0, int n0,
                                          char* As, char* Bs, int atomicCb) {
    const int tid = threadIdx.x;
    const int lane = tid & 63;
    const int wid = tid >> 6;
    const int wr = wid >> 1, wc = wid & 1;

    f32x4 zero4 = {0.f, 0.f, 0.f, 0.f};
    f32x4 acc[4][4];
#pragma unroll
    for (int i = 0; i < 4; ++i)
#pragma unroll
        for (int jx = 0; jx < 4; ++jx) acc[i][jx] = zero4;

    const int kIters = j.K >> 5;
    const int l15 = lane & 15, kg = lane >> 4;

    const int srow0 = wid * 32 + (lane >> 2);
    const int srow1 = srow0 + 16;
    const int c0 = (lane & 3) ^ (srow0 & 3);
    const int c1 = (lane & 3) ^ (srow1 & 3);
    int ar0 = m0 + srow0, ar1 = m0 + srow1;
    if (j.arev) {
        ar0 = (ar0 & ~511) | (511 - (ar0 & 511));
        ar1 = (ar1 & ~511) | (511 - (ar1 & 511));
    }
    const u16* ga0 = j.A + (size_t)ar0 * j.ldA + c0 * 8;
    const u16* ga1 = j.A + (size_t)ar1 * j.ldA + c1 * 8;
    const u16* gb0 = j.BT + (size_t)(n0 + srow0) * j.ldB + c0 * 8;
    const u16* gb1 = j.BT + (size_t)(n0 + srow1) * j.ldB + c1 * 8;
    char* ldsA0 = As + wid * 2048;
    char* ldsA1 = As + wid * 2048 + 1024;
    char* ldsB0 = Bs + wid * 2048;
    char* ldsB1 = Bs + wid * 2048 + 1024;

    for (int kt = 0; kt < kIters; ++kt) {
        const int k0 = kt * 32;
        __builtin_amdgcn_global_load_lds(AS1C(ga0 + k0), AS3(ldsA0), 16, 0, 0);
        __builtin_amdgcn_global_load_lds(AS1C(ga1 + k0), AS3(ldsA1), 16, 0, 0);
        __builtin_amdgcn_global_load_lds(AS1C(gb0 + k0), AS3(ldsB0), 16, 0, 0);
        __builtin_amdgcn_global_load_lds(AS1C(gb1 + k0), AS3(ldsB1), 16, 0, 0);
        __syncthreads();

        bf16x8 af[4], bfr[4];
#pragma unroll
        for (int mt = 0; mt < 4; ++mt) {
            int r = wr * 64 + mt * 16 + l15;
            af[mt] = *(const bf16x8*)(As + r * 64 + ((kg ^ (r & 3)) * 16));
        }
#pragma unroll
        for (int nt = 0; nt < 4; ++nt) {
            int r = wc * 64 + nt * 16 + l15;
            bfr[nt] = *(const bf16x8*)(Bs + r * 64 + ((kg ^ (r & 3)) * 16));
        }
#pragma unroll
        for (int mt = 0; mt < 4; ++mt)
#pragma unroll
            for (int nt = 0; nt < 4; ++nt)
                acc[mt][nt] = __builtin_amdgcn_mfma_f32_16x16x32_bf16(af[mt], bfr[nt], acc[mt][nt], 0, 0, 0);
        __syncthreads();
    }

#pragma unroll
    for (int nt = 0; nt < 4; ++nt) {
        int col = n0 + wc * 64 + nt * 16 + l15;
        float bv = (j.bias != nullptr && col < j.Nreal) ? j.bias[col] : 0.f;
#pragma unroll
        for (int mt = 0; mt < 4; ++mt) {
#pragma unroll
            for (int jx = 0; jx < 4; ++jx) {
                int m = m0 + wr * 64 + mt * 16 + kg * 4 + jx;
                int om = j.orev ? ((m & ~511) | (511 - (m & 511))) : m;
                om += j.orow_base;
                float v = acc[mt][nt][jx] + bv;
                if (atomicCb) {
                    float pv = __shfl_down(v, 1);
                    if ((l15 & 1) == 0 && col < j.Nreal)
                        st_atomic_u32((u32*)(j.Cb + (size_t)om * j.ldC + col),
                                      (u32)f2bf(v) | ((u32)f2bf(pv) << 16));
                } else if (col < j.Nreal) {
                    if (j.Cf) j.Cf[(size_t)om * j.ldC + col] = v;
                    else      j.Cb[(size_t)om * j.ldC + col] = f2bf(v);
                }
            }
        }
    }
}

__global__ __launch_bounds__(256) void gemm_multi4(GemmJob j0, GemmJob j1, GemmJob j2, GemmJob j3) {
    __shared__ char pool[16384];
    GemmJob j = (blockIdx.z == 0) ? j0 : (blockIdx.z == 1) ? j1 : (blockIdx.z == 2) ? j2 : j3;
    if ((int)blockIdx.y * 128 >= j.M) return;
    gemm_body(j, blockIdx.y * 128, blockIdx.x * 128, pool, pool + 8192, 0);
}

// ---------- K5: persistent LSTM recurrence + proj/logits chaser mega-kernel ----------
// blocks 0..63: rec (dir=bid>>5, blk=bid&31 owns 16 hu). Fence-free htag exchange.
// blocks 64..191: proj chasers: wait rec chunk ctr -> hall tile (atomic stores) -> band ctr
// blocks 192..: logits chasers: wait ONLY own band ctr (32 lines, s_sleep(127) backoff)
// Same-dispatch cross-XCD edges via coherence-point u32 atomics + vmcnt(0)-then-counter.
// WT_lin comes from prep (kernel-boundary coherence). Waits only target lower blockIdx.
__global__ __launch_bounds__(256) void lstm_fused(
    const float* __restrict__ Wc_f, const float* __restrict__ Wc_b,
    const float* __restrict__ xp_f, const float* __restrict__ xp_b,
    u64* __restrict__ htag,
    u16* __restrict__ hpre_f, u16* __restrict__ hpre_b,
    const u16* __restrict__ WT_lin,
    const u16* __restrict__ WprojTf, const u16* __restrict__ WprojTb,
    u16* __restrict__ hall, const float* __restrict__ b_lin,
    float* __restrict__ out, u32* __restrict__ ctr)
{
    __shared__ char pool[16384];
    const int tid = threadIdx.x;
    int bid = blockIdx.x;

    if (bid >= 64) {
        bid -= 64;
        if (bid < 128) {    // proj chaser: hall tile = hpre @ W_proj
            int dir = bid >> 6, r = bid & 63, y = r >> 2, x = r & 3;
            int m0 = y * 128, n0 = x * 128;
            if (tid == 0) {
                while (ld_atomic_u32(&ctr[8 + dir * 4 + (y & 3)]) < 32u) __builtin_amdgcn_s_sleep(32);
            }
            __syncthreads();
            GemmJob j = { dir ? hpre_b : hpre_f, dir ? WprojTb : WprojTf, nullptr, hall, nullptr,
                          2048, 512, 512, 512, 512, 512, 0, dir ? 1 : 0, dir ? 2048 : 0 };
            gemm_body(j, m0, n0, pool, pool + 8192, 1);
            asm volatile("s_waitcnt vmcnt(0)" ::: "memory");
            __syncthreads();
            if (tid == 0) {
                int obrow = j.orow_base + (j.orev ? ((m0 & ~511) | (511 - ((m0 + 127) & 511))) : m0);
                __hip_atomic_fetch_add(&ctr[16 + (obrow >> 7)], 1u, __ATOMIC_RELAXED, __HIP_MEMORY_SCOPE_AGENT);
            }
            return;
        }
        bid -= 128;
        {                   // logits chaser, ordered by availability chunk
            int cid = bid / (393 * 8), rr = bid % (393 * 8), bi = rr / 393, x = rr % 393;
            int band = (bi < 4) ? (bi * 4 + cid) : (16 + (bi - 4) * 4 + (3 - cid));
            if (tid == 0) {
                while (ld_atomic_u32(&ctr[16 + band]) < 4u) __builtin_amdgcn_s_sleep(127);
            }
            __syncthreads();
            GemmJob j = { hall, WT_lin, out, nullptr, b_lin,
                          4096, 50257, 512, 512, 512, 50257, 0, 0, 0 };
            gemm_body(j, band * 128, x * 128, pool, pool + 8192, 0);
            return;
        }
    }

    // ---------------- rec block ----------------
    __builtin_amdgcn_s_setprio(1);
    u16 (*hlds)[520] = (u16(*)[520])pool;                     // 4160 B
    float (*gsum)[4][16] = (float(*)[4][16])(pool + 4160);    // 1024 B
    float (*cbuf)[16] = (float(*)[16])(pool + 5184);          // 256 B

    const int dir = blockIdx.x >> 5;
    const int blk = blockIdx.x & 31;
    const int lane = tid & 63;
    const int wid = tid >> 6;          // wave = gate
    const int l15 = lane & 15;
    const int kg = lane >> 4;

    const float* wcsrc = dir ? Wc_b : Wc_f;
    const float* xp    = dir ? xp_b : xp_f;
    u16* hpre          = dir ? hpre_b : hpre_f;
    u64* ht            = htag + (size_t)dir * 2 * 4 * 256;

    bf16x8 wcf[16];
#pragma unroll
    for (int ks = 0; ks < 16; ++ks) {
        bf16x8 w;
#pragma unroll
        for (int e = 0; e < 8; ++e) {
            int k = ks * 32 + kg * 8 + e;
            w[e] = (short)f2bf(wcsrc[(size_t)k * 2048 + wid * 512 + blk * 16 + l15]);
        }
        wcf[ks] = w;
    }
    if (tid < 64) cbuf[tid >> 4][tid & 15] = 0.f;
    __syncthreads();

    const bf16x8 zero8 = {0, 0, 0, 0, 0, 0, 0, 0};
    const int b = tid >> 4, hu = tid & 15;

    for (int t = 0; t < 512; ++t) {
        float xpv0 = 0.f, xpv1 = 0.f, xpv2 = 0.f, xpv3 = 0.f;
        if (tid < 64) {
            const float* xr = xp + ((size_t)(b * 512 + t)) * 2048 + blk * 16 + hu;
            xpv0 = xr[0]; xpv1 = xr[512]; xpv2 = xr[1024]; xpv3 = xr[1536];
        }
        {   // batched tagged poll (data+flag in the same u64 words)
            const u64* src = ht + (size_t)(t & 1) * 4 * 256;
            const u64* p0 = src + tid;
            const u64* p1 = src + 256 + tid;
            const u64* p2 = src + 512 + tid;
            const u64* p3 = src + 768 + tid;
            const u32 target = (u32)t;
            u64 w0, w1, w2, w3;
            for (;;) {
                asm volatile(
                    "global_load_dwordx2 %0, %4, off sc0 sc1\n\t"
                    "global_load_dwordx2 %1, %5, off sc0 sc1\n\t"
                    "global_load_dwordx2 %2, %6, off sc0 sc1\n\t"
                    "global_load_dwordx2 %3, %7, off sc0 sc1\n\t"
                    "s_waitcnt vmcnt(0)"
                    : "=&v"(w0), "=&v"(w1), "=&v"(w2), "=&v"(w3)
                    : "v"(p0), "v"(p1), "v"(p2), "v"(p3)
                    : "memory");
                if (((u32)(w0 >> 32) == target) & ((u32)(w1 >> 32) == target) &
                    ((u32)(w2 >> 32) == target) & ((u32)(w3 >> 32) == target)) break;
                __builtin_amdgcn_s_sleep(1);
            }
            asm volatile("" ::: "memory");
            *(u32*)&hlds[0][tid * 2] = (u32)w0;
            *(u32*)&hlds[1][tid * 2] = (u32)w1;
            *(u32*)&hlds[2][tid * 2] = (u32)w2;
            *(u32*)&hlds[3][tid * 2] = (u32)w3;
        }
        __syncthreads();   // SYNC_A

        f32x4 a0 = {0,0,0,0}, a1 = {0,0,0,0}, a2 = {0,0,0,0}, a3 = {0,0,0,0};
#pragma unroll
        for (int ks = 0; ks < 16; ++ks) {
            bf16x8 a = zero8;
            if (l15 < 4) a = *(const bf16x8*)&hlds[l15][ks * 32 + kg * 8];
            switch (ks & 3) {
                case 0: a0 = __builtin_amdgcn_mfma_f32_16x16x32_bf16(a, wcf[ks], a0, 0, 0, 0); break;
                case 1: a1 = __builtin_amdgcn_mfma_f32_16x16x32_bf16(a, wcf[ks], a1, 0, 0, 0); break;
                case 2: a2 = __builtin_amdgcn_mfma_f32_16x16x32_bf16(a, wcf[ks], a2, 0, 0, 0); break;
                default: a3 = __builtin_amdgcn_mfma_f32_16x16x32_bf16(a, wcf[ks], a3, 0, 0, 0); break;
            }
        }
        f32x4 accs = (a0 + a1) + (a2 + a3);
        if (lane < 16) {
#pragma unroll
            for (int jx = 0; jx < 4; ++jx) gsum[wid][jx][lane] = accs[jx];
        }
        __syncthreads();   // SYNC_B

        if (tid < 64) {
            float pi = xpv0 + gsum[0][b][hu];
            float pf = xpv1 + gsum[1][b][hu];
            float pg = xpv2 + gsum[2][b][hu];
            float po = xpv3 + gsum[3][b][hu];
            float iv = 1.f / (1.f + expf(-pi));
            float fv = 1.f / (1.f + expf(-pf));
            float gv = tanhf(pg);
            float ov = 1.f / (1.f + expf(-po));
            float c2 = iv * gv + fv * cbuf[b][hu];
            cbuf[b][hu] = c2;
            u16 hpb = f2bf(ov * tanhf(c2));
            unsigned v = hpb;
            unsigned nb = (unsigned)__shfl_down((int)v, 1);
            if ((tid & 1) == 0) {
                u32 packed = v | (nb << 16);
                u64 val = ((u64)(u32)(t + 1) << 32) | (u64)packed;
                size_t idx = (size_t)(((t + 1) & 1) * 4 + b) * 256 + blk * 8 + (hu >> 1);
                __hip_atomic_store(&ht[idx], val, __ATOMIC_RELAXED, __HIP_MEMORY_SCOPE_AGENT);
                // hpre must be coherence-point visible to same-dispatch proj chasers
                st_atomic_u32((u32*)&hpre[(size_t)(b * 512 + t) * 512 + blk * 16 + hu], packed);
            }
        }
        if ((t & 127) == 127) {   // chunk boundary: drain wave-0 stores, then publish progress
            if (tid < 64) { asm volatile("s_waitcnt vmcnt(0)" ::: "memory"); }
            if (tid == 0)
                __hip_atomic_fetch_add(&ctr[8 + dir * 4 + (t >> 7)], 1u,
                                       __ATOMIC_RELAXED, __HIP_MEMORY_SCOPE_AGENT);
        }
    }
}

// ---------- host ----------
extern "C" void kernel_launch(void* const* d_in, const int* in_sizes, int n_in,
                              void* d_out, int out_size, void* d_ws, size_t ws_size,
                              hipStream_t stream) {
    const int*   tokens   = (const int*)d_in[0];
    const float* emb      = (const float*)d_in[1];
    const float* W_ih_f   = (const float*)d_in[2];
    const float* W_hh_f   = (const float*)d_in[3];
    const float* b_f      = (const float*)d_in[4];
    const float* W_proj_f = (const float*)d_in[5];
    const float* W_ih_b   = (const float*)d_in[6];
    const float* W_hh_b   = (const float*)d_in[7];
    const float* b_b      = (const float*)d_in[8];
    const float* W_proj_b = (const float*)d_in[9];
    const float* W_lin    = (const float*)d_in[10];
    const float* b_lin    = (const float*)d_in[11];
    float* out = (float*)d_out;

    char* ws = (char*)d_ws;
    size_t off = 0;
    auto alloc = [&](size_t bytes) -> char* {
        char* p = ws + off;
        off = (off + bytes + 255) & ~(size_t)255;
        return p;
    };
    u16* xemb     = (u16*)alloc(2048 * 320 * 2);
    u16* WT_ihf   = (u16*)alloc(2048 * 320 * 2);
    u16* WT_ihb   = (u16*)alloc(2048 * 320 * 2);
    u16* WT_hhf   = (u16*)alloc(2048 * 512 * 2);
    u16* WT_hhb   = (u16*)alloc(2048 * 512 * 2);
    u16* WprojTf  = (u16*)alloc(512 * 512 * 2);
    u16* WprojTb  = (u16*)alloc(512 * 512 * 2);
    u16* WprojAf  = (u16*)alloc(512 * 512 * 2);
    u16* WprojAb  = (u16*)alloc(512 * 512 * 2);
    u16* WT_lin   = (u16*)alloc((size_t)50304 * 512 * 2);
    float* xpf    = (float*)alloc((size_t)2048 * 2048 * 4);
    float* xpb    = (float*)alloc((size_t)2048 * 2048 * 4);
    float* Wc32f  = (float*)alloc((size_t)512 * 2048 * 4);
    float* Wc32b  = (float*)alloc((size_t)512 * 2048 * 4);
    u16* hpref    = (u16*)alloc((size_t)2048 * 512 * 2);
    u16* hpreb    = (u16*)alloc((size_t)2048 * 512 * 2);
    u16* hall     = (u16*)alloc((size_t)4096 * 512 * 2);
    u64* htag     = (u64*)alloc((size_t)2 * 2 * 4 * 256 * 8);
    u32* ctr      = (u32*)alloc(64 * 4);

    // 1) all prep (incl. W_lin transpose with plain stores) in one launch
    prep<<<2048 + 640 + 640 + 1024 + 1024 + 256 + 256 + 512 + 512 + 25152 + 1, 256, 0, stream>>>(
        tokens, emb, xemb,
        W_ih_f, WT_ihf, W_ih_b, WT_ihb,
        W_hh_f, WT_hhf, W_hh_b, WT_hhb,
        W_proj_f, WprojTf, W_proj_b, WprojTb,
        WprojAf, WprojAb, W_lin, WT_lin, htag, ctr);

    // 2) xp (fwd, bwd) + Wc (fwd, bwd) in one z=4 launch
    GemmJob jxf = {xemb, WT_ihf, xpf, nullptr, b_f, 2048, 2048, 320, 320, 320, 2048, 0, 0, 0};
    GemmJob jxb = {xemb, WT_ihb, xpb, nullptr, b_b, 2048, 2048, 320, 320, 320, 2048, 1, 0, 0};
    GemmJob jwf = {WprojAf, WT_hhf, Wc32f, nullptr, nullptr, 512, 2048, 512, 512, 512, 2048, 0, 0, 0};
    GemmJob jwb = {WprojAb, WT_hhb, Wc32b, nullptr, nullptr, 512, 2048, 512, 512, 512, 2048, 0, 0, 0};
    gemm_multi4<<<dim3(16, 16, 4), 256, 0, stream>>>(jxf, jxb, jwf, jwb);

    // 3) mega-kernel: rec + proj chasers + logits chasers
    lstm_fused<<<64 + 128 + 12576, 256, 0, stream>>>(
        Wc32f, Wc32b, xpf, xpb, htag, hpref, hpreb,
        WT_lin, WprojTf, WprojTb, hall, b_lin, out, ctr);
}